// Round 1
// baseline (2249.598 us; speedup 1.0000x reference)
//
#include <hip/hip_runtime.h>
#include <stdint.h>

typedef __bf16 v8bf __attribute__((ext_vector_type(8)));
typedef float  v4f  __attribute__((ext_vector_type(4)));

#define MFMA16(a,b,c) __builtin_amdgcn_mfma_f32_16x16x32_bf16((a),(b),(c),0,0,0)

__device__ __forceinline__ void g2l16(void* lds, const void* g) {
  __builtin_amdgcn_global_load_lds(
      (__attribute__((address_space(1))) unsigned int*)g,
      (__attribute__((address_space(3))) unsigned int*)lds, 16, 0, 0);
}

// ---------------- small prep kernels ----------------

__global__ void bnprep(const float* __restrict__ g, const float* __restrict__ b,
                       const float* __restrict__ m, const float* __restrict__ v,
                       float* __restrict__ sc, float* __restrict__ bi, int C) {
  int i = blockIdx.x * 256 + threadIdx.x;
  if (i < C) {
    float s = g[i] * rsqrtf(v[i] + 1e-5f);
    sc[i] = s;
    bi[i] = b[i] - m[i] * s;
  }
}

// OIHW fp32 -> [tap][co][ci] bf16 (co may be zero-padded)
__global__ void pack_w(const float* __restrict__ src, __bf16* __restrict__ dst,
                       int co_cnt, int co_src, int co_off, int co_tot, int ci, int taps) {
  int idx = blockIdx.x * 256 + threadIdx.x;
  if (idx >= co_cnt * ci) return;
  int c = idx % ci, co = idx / ci;
  for (int t = 0; t < taps; ++t) {
    float v = (co < co_src) ? src[((size_t)co * ci + c) * taps + t] : 0.f;
    dst[((size_t)t * co_tot + co_off + co) * ci + c] = (__bf16)v;
  }
}

// x NCHW fp32 -> xb [n][p][2048] bf16
__global__ void cast_x_k(const float* __restrict__ x, __bf16* __restrict__ xb) {
  __shared__ float tl[64][65];
  int p0 = blockIdx.x * 64, c0 = blockIdx.y * 64, n = blockIdx.z;
  const float* xin = x + (size_t)n * 2048 * 1024;
  for (int it = 0; it < 16; ++it) {
    int idx = it * 256 + threadIdx.x;
    int px = idx & 63, cl = idx >> 6;
    tl[px][cl] = xin[(size_t)(c0 + cl) * 1024 + p0 + px];
  }
  __syncthreads();
  for (int it = 0; it < 16; ++it) {
    int idx = it * 256 + threadIdx.x;
    int cl = idx & 63, px = idx >> 6;
    xb[((size_t)n * 1024 + p0 + px) * 2048 + c0 + cl] = (__bf16)tl[px][cl];
  }
}

// y12[:,512:1024] ([n][p][1024]) -> y2t [n][c][p] bf16
__global__ void trans_y2(const __bf16* __restrict__ y12, __bf16* __restrict__ y2t) {
  __shared__ __bf16 tl[64][72];
  int p0 = blockIdx.x * 64, c0 = blockIdx.y * 64, n = blockIdx.z;
  for (int it = 0; it < 16; ++it) {
    int idx = it * 256 + threadIdx.x;
    int cl = idx & 63, px = idx >> 6;
    tl[px][cl] = y12[((size_t)n * 1024 + p0 + px) * 1024 + 512 + c0 + cl];
  }
  __syncthreads();
  for (int it = 0; it < 16; ++it) {
    int idx = it * 256 + threadIdx.x;
    int px = idx & 63, cl = idx >> 6;
    y2t[((size_t)n * 512 + c0 + cl) * 1024 + p0 + px] = tl[px][cl];
  }
}

// ---------------- generic 128x128 GEMM (K contiguous both operands) ----------------
// D[m][n] = sum_k A[m][k]*B[n][k]   (B staged by rows n, k contiguous)
// mode 0: bf16 out[P*ldo + m]; mode 1: f32 out[m*ldo + P]; mode 2: mode0 + bf16 out2[m*1024 + P]
__global__ __launch_bounds__(256, 2)
void gemm_nt(const __bf16* __restrict__ A, const __bf16* __restrict__ B,
             size_t aB, size_t bB, int lda, int ldb, int kch, int mode,
             void* __restrict__ out, void* __restrict__ out2, size_t oB, int ldo) {
  __shared__ __align__(16) __bf16 tile[4 * 128 * 8];
  const int tid = threadIdx.x;
  const int lane = tid & 63, wv = tid >> 6;
  const int ln = lane & 15, q = lane >> 4;
  const int wm = wv >> 1, wn = wv & 1;
  const int p0 = blockIdx.x * 128, mb = blockIdx.y * 128, z = blockIdx.z;
  A += (size_t)z * aB; B += (size_t)z * bB;

  v4f acc[4][4];
#pragma unroll
  for (int mf = 0; mf < 4; ++mf) {
#pragma unroll
    for (int nf = 0; nf < 4; ++nf) {
#pragma unroll
      for (int r = 0; r < 4; ++r) acc[mf][nf][r] = 0.f;
    }
  }
  const __bf16* pa[4];
#pragma unroll
  for (int mf = 0; mf < 4; ++mf)
    pa[mf] = A + (size_t)(mb + wm * 64 + mf * 16 + ln) * lda + q * 8;

  for (int kc = 0; kc < kch; ++kc) {
    const int c0 = kc * 32;
#pragma unroll
    for (int t2 = 0; t2 < 2; ++t2) {
      g2l16(&tile[(wv * 128 + t2 * 64) * 8],
            B + (size_t)(p0 + t2 * 64 + lane) * ldb + c0 + wv * 8);
    }
    __syncthreads();
    v8bf bfr[4];
#pragma unroll
    for (int nf = 0; nf < 4; ++nf)
      bfr[nf] = *(const v8bf*)&tile[(q * 128 + wn * 64 + nf * 16 + ln) * 8];
#pragma unroll
    for (int mf = 0; mf < 4; ++mf) {
      v8bf af = *(const v8bf*)(pa[mf] + c0);
#pragma unroll
      for (int nf = 0; nf < 4; ++nf)
        acc[mf][nf] = MFMA16(af, bfr[nf], acc[mf][nf]);
    }
    __syncthreads();
  }

#pragma unroll
  for (int mf = 0; mf < 4; ++mf) {
    const int m_l = wm * 64 + mf * 16 + q * 4;
#pragma unroll
    for (int nf = 0; nf < 4; ++nf) {
      const int n_l = wn * 64 + nf * 16 + ln;
      const int P = p0 + n_l;
      if (mode == 1) {
        float* o = (float*)out + (size_t)z * oB;
#pragma unroll
        for (int r = 0; r < 4; ++r)
          o[(size_t)(mb + m_l + r) * ldo + P] = acc[mf][nf][r];
      } else {
        __bf16* o = (__bf16*)out + (size_t)z * oB;
        union { __bf16 h[4]; uint2 u; } pk;
#pragma unroll
        for (int r = 0; r < 4; ++r) pk.h[r] = (__bf16)acc[mf][nf][r];
        *(uint2*)(o + (size_t)P * ldo + mb + m_l) = pk.u;
        if (mode == 2) {
          __bf16* o2 = (__bf16*)out2 + (size_t)z * oB;
#pragma unroll
          for (int r = 0; r < 4; ++r)
            o2[(size_t)(mb + m_l + r) * 1024 + P] = pk.h[r];
        }
      }
    }
  }
}

// ---------------- 3x3 conv on 32x32 images, implicit GEMM 128x128 ----------------
// in: [n][1024][CI] bf16 NHWC ; wp: [9][CO][CI] ; out: [n][1024][CO] bf16, bn+relu
template <int CI, int KCH>
__global__ __launch_bounds__(256, 2)
void conv3x3_32(const __bf16* __restrict__ in, const __bf16* __restrict__ wp,
                const float* __restrict__ sc, const float* __restrict__ bi,
                __bf16* __restrict__ out, const int CO) {
  __shared__ __align__(16) __bf16 tile[4 * 204 * 8];  // [kgrp][6*34 pix][8ci]
  __shared__ float s_sc[128], s_bi[128];
  const int tid = threadIdx.x;
  const int lane = tid & 63, wv = tid >> 6;
  const int ln = lane & 15, q = lane >> 4;
  const int pblk = blockIdx.x, cb = blockIdx.y;
  const int n = pblk >> 3, y0 = (pblk & 7) << 2;
  const int wm = wv >> 1, wn = wv & 1;

  if (tid < 128) { int c = cb * 128 + tid; s_sc[tid] = sc[c]; s_bi[tid] = bi[c]; }
  for (int t = tid; t < 816; t += 256) ((uint4*)tile)[t] = make_uint4(0, 0, 0, 0);

  v4f acc[4][4];
#pragma unroll
  for (int mf = 0; mf < 4; ++mf) {
#pragma unroll
    for (int nf = 0; nf < 4; ++nf) {
#pragma unroll
      for (int r = 0; r < 4; ++r) acc[mf][nf][r] = 0.f;
    }
  }
  const __bf16* pa[4];
#pragma unroll
  for (int mf = 0; mf < 4; ++mf) {
    int co = cb * 128 + wm * 64 + mf * 16 + ln;
    pa[mf] = wp + (size_t)co * CI + q * 8;
  }
  int pixb[4];
#pragma unroll
  for (int nf = 0; nf < 4; ++nf) {
    int n_l = wn * 64 + nf * 16 + ln;
    pixb[nf] = (n_l >> 5) * 34 + (n_l & 31);
  }
  const __bf16* inb = in + (size_t)n * 1024 * CI;
  __syncthreads();

  for (int kc = 0; kc < KCH; ++kc) {
    const int ci0 = kc * 32;
    if (lane < 32) {
#pragma unroll
      for (int t2 = 0; t2 < 6; ++t2) {
        int y = y0 - 1 + t2;
        if (y >= 0 && y < 32)
          g2l16(&tile[(wv * 204 + t2 * 34 + 1) * 8],
                inb + ((size_t)(y * 32 + lane) * CI + ci0 + wv * 8));
      }
    }
    __syncthreads();
#pragma unroll
    for (int tap = 0; tap < 9; ++tap) {
      const int ty = tap / 3, tx = tap % 3;
      v8bf bfr[4];
#pragma unroll
      for (int nf = 0; nf < 4; ++nf)
        bfr[nf] = *(const v8bf*)&tile[(q * 204 + pixb[nf] + ty * 34 + tx) * 8];
      const size_t toff = (size_t)tap * CO * CI + ci0;
#pragma unroll
      for (int mf = 0; mf < 4; ++mf) {
        v8bf af = *(const v8bf*)(pa[mf] + toff);
#pragma unroll
        for (int nf = 0; nf < 4; ++nf)
          acc[mf][nf] = MFMA16(af, bfr[nf], acc[mf][nf]);
      }
    }
    __syncthreads();
  }

#pragma unroll
  for (int mf = 0; mf < 4; ++mf) {
    const int m_l = wm * 64 + mf * 16 + q * 4;
#pragma unroll
    for (int nf = 0; nf < 4; ++nf) {
      const int n_l = wn * 64 + nf * 16 + ln;
      const int p_img = (y0 + (n_l >> 5)) * 32 + (n_l & 31);
      union { __bf16 h[4]; uint2 u; } pk;
#pragma unroll
      for (int r = 0; r < 4; ++r) {
        float v = acc[mf][nf][r] * s_sc[m_l + r] + s_bi[m_l + r];
        pk.h[r] = (__bf16)fmaxf(v, 0.f);
      }
      *(uint2*)(out + (size_t)(n * 1024 + p_img) * CO + cb * 128 + m_l) = pk.u;
    }
  }
}

// ---------------- conv4a: fused x8 bilinear upsample + 3x3 conv 512->256 ----------------
// y3: [n][1024][512] bf16 ; out y4: [n][256*256][256] bf16, bn4+relu
__global__ __launch_bounds__(256, 2)
void conv4a_up(const __bf16* __restrict__ y3, const __bf16* __restrict__ wp,
               const float* __restrict__ sc, const float* __restrict__ bi,
               __bf16* __restrict__ out) {
  __shared__ __align__(16) __bf16 tile[4 * 204 * 8];
  __shared__ float s_sc[128], s_bi[128];
  const int tid = threadIdx.x;
  const int lane = tid & 63, wv = tid >> 6;
  const int ln = lane & 15, q = lane >> 4;
  const int xblk = blockIdx.x;
  const int cb = blockIdx.y & 1, strip = blockIdx.y >> 1;
  const int n = blockIdx.z;
  const int oy0 = strip * 4, ox0 = xblk * 32;
  const int wm = wv >> 1, wn = wv & 1;

  if (tid < 128) { int c = cb * 128 + tid; s_sc[tid] = sc[c]; s_bi[tid] = bi[c]; }

  v4f acc[4][4];
#pragma unroll
  for (int mf = 0; mf < 4; ++mf) {
#pragma unroll
    for (int nf = 0; nf < 4; ++nf) {
#pragma unroll
      for (int r = 0; r < 4; ++r) acc[mf][nf][r] = 0.f;
    }
  }
  const __bf16* pa[4];
#pragma unroll
  for (int mf = 0; mf < 4; ++mf) {
    int co = cb * 128 + wm * 64 + mf * 16 + ln;
    pa[mf] = wp + (size_t)co * 512 + q * 8;
  }
  int pixb[4];
#pragma unroll
  for (int nf = 0; nf < 4; ++nf) {
    int n_l = wn * 64 + nf * 16 + ln;
    pixb[nf] = (n_l >> 5) * 34 + (n_l & 31);
  }
  const __bf16* src = y3 + (size_t)n * 1024 * 512;

  for (int kc = 0; kc < 16; ++kc) {
    const int ci0 = kc * 32;
    // expand bilinear-upsampled window [6 rows][34 cols] x 32ci into LDS
    for (int t = tid; t < 816; t += 256) {
      int s = t / 204, pix = t - s * 204;
      int rr = pix / 34, cc = pix - rr * 34;
      int fy = oy0 - 1 + rr, fx = ox0 - 1 + cc;
      float res[8];
#pragma unroll
      for (int i = 0; i < 8; ++i) res[i] = 0.f;
      if (fy >= 0 && fy <= 255 && fx >= 0 && fx <= 255) {
        float syf = fy * (31.0f / 255.0f);
        int yy0 = (int)syf; float wy = syf - yy0;
        int yy1 = yy0 < 31 ? yy0 + 1 : 31;
        float sxf = fx * (31.0f / 255.0f);
        int xx0 = (int)sxf; float wx = sxf - xx0;
        int xx1 = xx0 < 31 ? xx0 + 1 : 31;
        const int cof = ci0 + s * 8;
        v8bf v00 = *(const v8bf*)(src + ((size_t)(yy0 * 32 + xx0) * 512 + cof));
        v8bf v01 = *(const v8bf*)(src + ((size_t)(yy0 * 32 + xx1) * 512 + cof));
        v8bf v10 = *(const v8bf*)(src + ((size_t)(yy1 * 32 + xx0) * 512 + cof));
        v8bf v11 = *(const v8bf*)(src + ((size_t)(yy1 * 32 + xx1) * 512 + cof));
        float w00 = (1.f - wy) * (1.f - wx), w01 = (1.f - wy) * wx;
        float w10 = wy * (1.f - wx), w11 = wy * wx;
#pragma unroll
        for (int i = 0; i < 8; ++i)
          res[i] = w00 * (float)v00[i] + w01 * (float)v01[i] +
                   w10 * (float)v10[i] + w11 * (float)v11[i];
      }
      v8bf val;
#pragma unroll
      for (int i = 0; i < 8; ++i) val[i] = (__bf16)res[i];
      *(v8bf*)&tile[t * 8] = val;
    }
    __syncthreads();
#pragma unroll
    for (int tap = 0; tap < 9; ++tap) {
      const int ty = tap / 3, tx = tap % 3;
      v8bf bfr[4];
#pragma unroll
      for (int nf = 0; nf < 4; ++nf)
        bfr[nf] = *(const v8bf*)&tile[(q * 204 + pixb[nf] + ty * 34 + tx) * 8];
      const size_t toff = (size_t)tap * 256 * 512 + ci0;
#pragma unroll
      for (int mf = 0; mf < 4; ++mf) {
        v8bf af = *(const v8bf*)(pa[mf] + toff);
#pragma unroll
        for (int nf = 0; nf < 4; ++nf)
          acc[mf][nf] = MFMA16(af, bfr[nf], acc[mf][nf]);
      }
    }
    __syncthreads();
  }

#pragma unroll
  for (int mf = 0; mf < 4; ++mf) {
    const int m_l = wm * 64 + mf * 16 + q * 4;
#pragma unroll
    for (int nf = 0; nf < 4; ++nf) {
      const int n_l = wn * 64 + nf * 16 + ln;
      const int oy = oy0 + (n_l >> 5), ox = ox0 + (n_l & 31);
      union { __bf16 h[4]; uint2 u; } pk;
#pragma unroll
      for (int r = 0; r < 4; ++r) {
        float v = acc[mf][nf][r] * s_sc[m_l + r] + s_bi[m_l + r];
        pk.h[r] = (__bf16)fmaxf(v, 0.f);
      }
      *(uint2*)(out + ((size_t)n * 65536 + (size_t)oy * 256 + ox) * 256 + cb * 128 + m_l) = pk.u;
    }
  }
}

// ---------------- conv4b: 3x3 conv 256->19 on 256x256, fp32 NCHW out ----------------
__global__ __launch_bounds__(256, 2)
void conv4b_k(const __bf16* __restrict__ y4, const __bf16* __restrict__ wp,
              float* __restrict__ outp) {
  __shared__ __align__(16) __bf16 tile[4 * 204 * 8];
  const int tid = threadIdx.x;
  const int lane = tid & 63, wv = tid >> 6;
  const int ln = lane & 15, q = lane >> 4;
  const int xblk = blockIdx.x, strip = blockIdx.y, n = blockIdx.z;
  const int oy0 = strip * 4, ox0 = xblk * 32;

  for (int t = tid; t < 816; t += 256) ((uint4*)tile)[t] = make_uint4(0, 0, 0, 0);

  v4f acc[2][2];
#pragma unroll
  for (int mf = 0; mf < 2; ++mf) {
#pragma unroll
    for (int nf = 0; nf < 2; ++nf) {
#pragma unroll
      for (int r = 0; r < 4; ++r) acc[mf][nf][r] = 0.f;
    }
  }
  const __bf16* pa[2];
#pragma unroll
  for (int mf = 0; mf < 2; ++mf)
    pa[mf] = wp + (size_t)(mf * 16 + ln) * 256 + q * 8;
  int pixb[2];
#pragma unroll
  for (int nf = 0; nf < 2; ++nf) {
    int n_l = wv * 32 + nf * 16 + ln;
    pixb[nf] = (n_l >> 5) * 34 + (n_l & 31);
  }
  const __bf16* src = y4 + (size_t)n * 65536 * 256;
  __syncthreads();

  for (int kc = 0; kc < 8; ++kc) {
    const int ci0 = kc * 32;
#pragma unroll
    for (int t2 = 0; t2 < 6; ++t2) {
      int y = oy0 - 1 + t2;
      int gx = ox0 - 1 + lane;
      if (y >= 0 && y < 256 && lane < 34 && gx >= 0 && gx < 256)
        g2l16(&tile[(wv * 204 + t2 * 34) * 8],
              src + ((size_t)(y * 256 + gx) * 256 + ci0 + wv * 8));
    }
    __syncthreads();
#pragma unroll
    for (int tap = 0; tap < 9; ++tap) {
      const int ty = tap / 3, tx = tap % 3;
      v8bf bfr[2];
#pragma unroll
      for (int nf = 0; nf < 2; ++nf)
        bfr[nf] = *(const v8bf*)&tile[(q * 204 + pixb[nf] + ty * 34 + tx) * 8];
      const size_t toff = (size_t)tap * 32 * 256 + ci0;
#pragma unroll
      for (int mf = 0; mf < 2; ++mf) {
        v8bf af = *(const v8bf*)(pa[mf] + toff);
#pragma unroll
        for (int nf = 0; nf < 2; ++nf)
          acc[mf][nf] = MFMA16(af, bfr[nf], acc[mf][nf]);
      }
    }
    __syncthreads();
  }

#pragma unroll
  for (int mf = 0; mf < 2; ++mf) {
    const int m_l = mf * 16 + q * 4;
#pragma unroll
    for (int nf = 0; nf < 2; ++nf) {
      const int n_l = wv * 32 + nf * 16 + ln;
      const int oy = oy0 + (n_l >> 5), ox = ox0 + (n_l & 31);
#pragma unroll
      for (int r = 0; r < 4; ++r) {
        int co = m_l + r;
        if (co < 19)
          outp[(((size_t)n * 19 + co) * 256 + oy) * 256 + ox] = acc[mf][nf][r];
      }
    }
  }
}

// ---------------- softmax kernels ----------------

__global__ void softmax1024(const float* __restrict__ S, __bf16* __restrict__ O) {
  __shared__ float red[256];
  const int row = blockIdx.x, tid = threadIdx.x;
  const float* p = S + (size_t)row * 1024;
  float v0 = p[tid], v1 = p[tid + 256], v2 = p[tid + 512], v3 = p[tid + 768];
  float m = fmaxf(fmaxf(v0, v1), fmaxf(v2, v3));
  red[tid] = m; __syncthreads();
  for (int s = 128; s > 0; s >>= 1) { if (tid < s) red[tid] = fmaxf(red[tid], red[tid + s]); __syncthreads(); }
  m = red[0]; __syncthreads();
  v0 = __expf(v0 - m); v1 = __expf(v1 - m); v2 = __expf(v2 - m); v3 = __expf(v3 - m);
  red[tid] = v0 + v1 + v2 + v3; __syncthreads();
  for (int s = 128; s > 0; s >>= 1) { if (tid < s) red[tid] += red[tid + s]; __syncthreads(); }
  float inv = 1.0f / red[0];
  __bf16* o = O + (size_t)row * 1024;
  o[tid] = (__bf16)(v0 * inv); o[tid + 256] = (__bf16)(v1 * inv);
  o[tid + 512] = (__bf16)(v2 * inv); o[tid + 768] = (__bf16)(v3 * inv);
}

// softmax rows of Scc[c][d] (512 wide), writes transposed: O[d*512+c] = Asm[c][d]
__global__ void softmaxT512(const float* __restrict__ S, __bf16* __restrict__ O) {
  __shared__ float red[256];
  const int row = blockIdx.x, tid = threadIdx.x;
  const float* p = S + (size_t)row * 512;
  float v0 = p[tid], v1 = p[tid + 256];
  float m = fmaxf(v0, v1);
  red[tid] = m; __syncthreads();
  for (int s = 128; s > 0; s >>= 1) { if (tid < s) red[tid] = fmaxf(red[tid], red[tid + s]); __syncthreads(); }
  m = red[0]; __syncthreads();
  v0 = __expf(v0 - m); v1 = __expf(v1 - m);
  red[tid] = v0 + v1; __syncthreads();
  for (int s = 128; s > 0; s >>= 1) { if (tid < s) red[tid] += red[tid + s]; __syncthreads(); }
  float inv = 1.0f / red[0];
  int n = row >> 9, c = row & 511;
  __bf16* o = O + (size_t)n * 262144 + c;
  o[(size_t)tid * 512] = (__bf16)(v0 * inv);
  o[(size_t)(tid + 256) * 512] = (__bf16)(v1 * inv);
}

// z = y1 + y2 + gamma*E + beta*X  (all [n*1024][512]-ish)
__global__ void combine_z(const __bf16* __restrict__ y12, const __bf16* __restrict__ E,
                          const __bf16* __restrict__ X, const float* __restrict__ gp,
                          const float* __restrict__ bp, __bf16* __restrict__ z) {
  size_t i = (size_t)blockIdx.x * 256 + threadIdx.x;
  int pg = (int)(i >> 9), c = (int)(i & 511);
  float g = gp[0], b = bp[0];
  float v = (float)y12[(size_t)pg * 1024 + c] + (float)y12[(size_t)pg * 1024 + 512 + c] +
            g * (float)E[i] + b * (float)X[i];
  z[i] = (__bf16)v;
}

// ---------------- launcher ----------------

extern "C" void kernel_launch(void* const* d_in, const int* in_sizes, int n_in,
                              void* d_out, int out_size, void* d_ws, size_t ws_size,
                              hipStream_t stream) {
  const float* x    = (const float*)d_in[0];
  const float* w1   = (const float*)d_in[1];
  const float* bn1g = (const float*)d_in[2];
  const float* bn1b = (const float*)d_in[3];
  const float* bn1m = (const float*)d_in[4];
  const float* bn1v = (const float*)d_in[5];
  const float* w2   = (const float*)d_in[6];
  const float* bn2g = (const float*)d_in[7];
  const float* bn2b = (const float*)d_in[8];
  const float* bn2m = (const float*)d_in[9];
  const float* bn2v = (const float*)d_in[10];
  const float* wB   = (const float*)d_in[11];
  const float* gam  = (const float*)d_in[12];
  const float* bet  = (const float*)d_in[13];
  const float* w3   = (const float*)d_in[14];
  const float* bn3g = (const float*)d_in[15];
  const float* bn3b = (const float*)d_in[16];
  const float* bn3m = (const float*)d_in[17];
  const float* bn3v = (const float*)d_in[18];
  const float* w4a  = (const float*)d_in[19];
  const float* bn4g = (const float*)d_in[20];
  const float* bn4b = (const float*)d_in[21];
  const float* bn4m = (const float*)d_in[22];
  const float* bn4v = (const float*)d_in[23];
  const float* w4b  = (const float*)d_in[24];

  char* ws = (char*)d_ws;
  size_t off = 0;
  auto take = [&](size_t bytes) -> char* {
    char* p = ws + off;
    off += (bytes + 255) & ~(size_t)255;
    return p;
  };
  __bf16* w12b  = (__bf16*)take(9ULL * 1024 * 2048 * 2);
  __bf16* w3b   = (__bf16*)take(9ULL * 512 * 512 * 2);
  __bf16* w4ab  = (__bf16*)take(9ULL * 256 * 512 * 2);
  __bf16* w4bb  = (__bf16*)take(9ULL * 32 * 256 * 2);
  __bf16* wBb   = (__bf16*)take(512ULL * 512 * 2);
  float*  sc12  = (float*)take(1024 * 4);
  float*  bi12  = (float*)take(1024 * 4);
  float*  sc3   = (float*)take(512 * 4);
  float*  bi3   = (float*)take(512 * 4);
  float*  sc4   = (float*)take(256 * 4);
  float*  bi4   = (float*)take(256 * 4);
  __bf16* xb    = (__bf16*)take(4ULL * 1024 * 2048 * 2);
  __bf16* y12   = (__bf16*)take(4ULL * 1024 * 1024 * 2);
  __bf16* Bm_pc = (__bf16*)take(4ULL * 1024 * 512 * 2);
  __bf16* Bm_cp = (__bf16*)take(4ULL * 512 * 1024 * 2);
  float*  Smat  = (float*)take(4ULL * 1024 * 1024 * 4);
  __bf16* Ssm   = (__bf16*)take(4ULL * 1024 * 1024 * 2);
  __bf16* E_pc  = (__bf16*)take(4ULL * 1024 * 512 * 2);
  __bf16* y2t   = (__bf16*)take(4ULL * 512 * 1024 * 2);
  float*  Scc   = (float*)take(4ULL * 512 * 512 * 4);
  __bf16* AsmT  = (__bf16*)take(4ULL * 512 * 512 * 2);
  __bf16* X_pc  = (__bf16*)take(4ULL * 1024 * 512 * 2);
  __bf16* zb    = (__bf16*)take(4ULL * 1024 * 512 * 2);
  __bf16* y4    = (__bf16*)take(4ULL * 65536 * 256 * 2);
  __bf16* y3    = (__bf16*)take(4ULL * 1024 * 512 * 2);

  // prep
  bnprep<<<2, 256, 0, stream>>>(bn1g, bn1b, bn1m, bn1v, sc12, bi12, 512);
  bnprep<<<2, 256, 0, stream>>>(bn2g, bn2b, bn2m, bn2v, sc12 + 512, bi12 + 512, 512);
  bnprep<<<2, 256, 0, stream>>>(bn3g, bn3b, bn3m, bn3v, sc3, bi3, 512);
  bnprep<<<1, 256, 0, stream>>>(bn4g, bn4b, bn4m, bn4v, sc4, bi4, 256);
  pack_w<<<4096, 256, 0, stream>>>(w1, w12b, 512, 512, 0, 1024, 2048, 9);
  pack_w<<<4096, 256, 0, stream>>>(w2, w12b, 512, 512, 512, 1024, 2048, 9);
  pack_w<<<1024, 256, 0, stream>>>(w3, w3b, 512, 512, 0, 512, 512, 9);
  pack_w<<<512, 256, 0, stream>>>(w4a, w4ab, 256, 256, 0, 256, 512, 9);
  pack_w<<<32, 256, 0, stream>>>(w4b, w4bb, 32, 19, 0, 32, 256, 9);
  pack_w<<<1024, 256, 0, stream>>>(wB, wBb, 512, 512, 0, 512, 512, 1);
  cast_x_k<<<dim3(16, 32, 4), 256, 0, stream>>>(x, xb);

  // conv1 + conv2 fused as one GEMM (co 0..511 = conv1, 512..1023 = conv2)
  conv3x3_32<2048, 64><<<dim3(32, 8), 256, 0, stream>>>(xb, w12b, sc12, bi12, y12, 1024);

  // position attention
  gemm_nt<<<dim3(8, 4, 4), 256, 0, stream>>>(wBb, y12, 0, 1048576, 512, 1024, 16, 2,
                                             Bm_pc, Bm_cp, 524288, 512);
  gemm_nt<<<dim3(8, 8, 4), 256, 0, stream>>>(Bm_pc, Bm_pc, 524288, 524288, 512, 512, 16, 1,
                                             Smat, nullptr, 1048576, 1024);
  softmax1024<<<4096, 256, 0, stream>>>(Smat, Ssm);
  gemm_nt<<<dim3(8, 4, 4), 256, 0, stream>>>(Bm_cp, Ssm, 524288, 1048576, 1024, 1024, 32, 0,
                                             E_pc, nullptr, 524288, 512);

  // channel attention
  trans_y2<<<dim3(16, 8, 4), 256, 0, stream>>>(y12, y2t);
  gemm_nt<<<dim3(4, 4, 4), 256, 0, stream>>>(y2t, y2t, 524288, 524288, 1024, 1024, 32, 1,
                                             Scc, nullptr, 262144, 512);
  softmaxT512<<<2048, 256, 0, stream>>>(Scc, AsmT);
  gemm_nt<<<dim3(8, 4, 4), 256, 0, stream>>>(AsmT, y12 + 512, 262144, 1048576, 512, 1024, 16, 0,
                                             X_pc, nullptr, 524288, 512);

  // z = pa + ca
  combine_z<<<8192, 256, 0, stream>>>(y12, E_pc, X_pc, gam, bet, zb);

  // conv3
  conv3x3_32<512, 16><<<dim3(32, 4), 256, 0, stream>>>(zb, w3b, sc3, bi3, y3, 512);

  // conv4a fused with x8 bilinear upsample
  conv4a_up<<<dim3(8, 128, 4), 256, 0, stream>>>(y3, w4ab, sc4, bi4, y4);

  // conv4b -> d_out (fp32 NCHW)
  conv4b_k<<<dim3(8, 64, 4), 256, 0, stream>>>(y4, w4bb, (float*)d_out);
}

// Round 2
// 2133.128 us; speedup vs baseline: 1.0546x; 1.0546x over previous
//
#include <hip/hip_runtime.h>
#include <stdint.h>

typedef __bf16 v8bf __attribute__((ext_vector_type(8)));
typedef float  v4f  __attribute__((ext_vector_type(4)));

#define MFMA16(a,b,c) __builtin_amdgcn_mfma_f32_16x16x32_bf16((a),(b),(c),0,0,0)

__device__ __forceinline__ void g2l16(void* lds, const void* g) {
  __builtin_amdgcn_global_load_lds(
      (__attribute__((address_space(1))) unsigned int*)g,
      (__attribute__((address_space(3))) unsigned int*)lds, 16, 0, 0);
}

// ---------------- small prep kernels ----------------

__global__ void bnprep(const float* __restrict__ g, const float* __restrict__ b,
                       const float* __restrict__ m, const float* __restrict__ v,
                       float* __restrict__ sc, float* __restrict__ bi, int C) {
  int i = blockIdx.x * 256 + threadIdx.x;
  if (i < C) {
    float s = g[i] * rsqrtf(v[i] + 1e-5f);
    sc[i] = s;
    bi[i] = b[i] - m[i] * s;
  }
}

// OIHW fp32 -> [tap][co][ci] bf16 (co may be zero-padded)
__global__ void pack_w(const float* __restrict__ src, __bf16* __restrict__ dst,
                       int co_cnt, int co_src, int co_off, int co_tot, int ci, int taps) {
  int idx = blockIdx.x * 256 + threadIdx.x;
  if (idx >= co_cnt * ci) return;
  int c = idx % ci, co = idx / ci;
  for (int t = 0; t < taps; ++t) {
    float v = (co < co_src) ? src[((size_t)co * ci + c) * taps + t] : 0.f;
    dst[((size_t)t * co_tot + co_off + co) * ci + c] = (__bf16)v;
  }
}

// x NCHW fp32 -> xb [n][p][2048] bf16
__global__ void cast_x_k(const float* __restrict__ x, __bf16* __restrict__ xb) {
  __shared__ float tl[64][65];
  int p0 = blockIdx.x * 64, c0 = blockIdx.y * 64, n = blockIdx.z;
  const float* xin = x + (size_t)n * 2048 * 1024;
  for (int it = 0; it < 16; ++it) {
    int idx = it * 256 + threadIdx.x;
    int px = idx & 63, cl = idx >> 6;
    tl[px][cl] = xin[(size_t)(c0 + cl) * 1024 + p0 + px];
  }
  __syncthreads();
  for (int it = 0; it < 16; ++it) {
    int idx = it * 256 + threadIdx.x;
    int cl = idx & 63, px = idx >> 6;
    xb[((size_t)n * 1024 + p0 + px) * 2048 + c0 + cl] = (__bf16)tl[px][cl];
  }
}

// y12[:,512:1024] ([n][p][1024]) -> y2t [n][c][p] bf16
__global__ void trans_y2(const __bf16* __restrict__ y12, __bf16* __restrict__ y2t) {
  __shared__ __bf16 tl[64][72];
  int p0 = blockIdx.x * 64, c0 = blockIdx.y * 64, n = blockIdx.z;
  for (int it = 0; it < 16; ++it) {
    int idx = it * 256 + threadIdx.x;
    int cl = idx & 63, px = idx >> 6;
    tl[px][cl] = y12[((size_t)n * 1024 + p0 + px) * 1024 + 512 + c0 + cl];
  }
  __syncthreads();
  for (int it = 0; it < 16; ++it) {
    int idx = it * 256 + threadIdx.x;
    int px = idx & 63, cl = idx >> 6;
    y2t[((size_t)n * 512 + c0 + cl) * 1024 + p0 + px] = tl[px][cl];
  }
}

// ---------------- generic 128x128 GEMM (K contiguous both operands) ----------------
// D[m][n] = sum_k A[m][k]*B[n][k]   (B staged by rows n, k contiguous)
// mode 0: bf16 out[P*ldo + m]; mode 1: f32 out[m*ldo + P]; mode 2: mode0 + bf16 out2[m*1024 + P]
__global__ __launch_bounds__(256, 2)
void gemm_nt(const __bf16* __restrict__ A, const __bf16* __restrict__ B,
             size_t aB, size_t bB, int lda, int ldb, int kch, int mode,
             void* __restrict__ out, void* __restrict__ out2, size_t oB, int ldo) {
  __shared__ __align__(16) __bf16 tile[4 * 128 * 8];
  const int tid = threadIdx.x;
  const int lane = tid & 63, wv = tid >> 6;
  const int ln = lane & 15, q = lane >> 4;
  const int wm = wv >> 1, wn = wv & 1;
  const int p0 = blockIdx.x * 128, mb = blockIdx.y * 128, z = blockIdx.z;
  A += (size_t)z * aB; B += (size_t)z * bB;

  v4f acc[4][4];
#pragma unroll
  for (int mf = 0; mf < 4; ++mf) {
#pragma unroll
    for (int nf = 0; nf < 4; ++nf) {
#pragma unroll
      for (int r = 0; r < 4; ++r) acc[mf][nf][r] = 0.f;
    }
  }
  const __bf16* pa[4];
#pragma unroll
  for (int mf = 0; mf < 4; ++mf)
    pa[mf] = A + (size_t)(mb + wm * 64 + mf * 16 + ln) * lda + q * 8;

  for (int kc = 0; kc < kch; ++kc) {
    const int c0 = kc * 32;
#pragma unroll
    for (int t2 = 0; t2 < 2; ++t2) {
      g2l16(&tile[(wv * 128 + t2 * 64) * 8],
            B + (size_t)(p0 + t2 * 64 + lane) * ldb + c0 + wv * 8);
    }
    __syncthreads();
    v8bf bfr[4];
#pragma unroll
    for (int nf = 0; nf < 4; ++nf)
      bfr[nf] = *(const v8bf*)&tile[(q * 128 + wn * 64 + nf * 16 + ln) * 8];
#pragma unroll
    for (int mf = 0; mf < 4; ++mf) {
      v8bf af = *(const v8bf*)(pa[mf] + c0);
#pragma unroll
      for (int nf = 0; nf < 4; ++nf)
        acc[mf][nf] = MFMA16(af, bfr[nf], acc[mf][nf]);
    }
    __syncthreads();
  }

#pragma unroll
  for (int mf = 0; mf < 4; ++mf) {
    const int m_l = wm * 64 + mf * 16 + q * 4;
#pragma unroll
    for (int nf = 0; nf < 4; ++nf) {
      const int n_l = wn * 64 + nf * 16 + ln;
      const int P = p0 + n_l;
      if (mode == 1) {
        float* o = (float*)out + (size_t)z * oB;
#pragma unroll
        for (int r = 0; r < 4; ++r)
          o[(size_t)(mb + m_l + r) * ldo + P] = acc[mf][nf][r];
      } else {
        __bf16* o = (__bf16*)out + (size_t)z * oB;
        union { __bf16 h[4]; uint2 u; } pk;
#pragma unroll
        for (int r = 0; r < 4; ++r) pk.h[r] = (__bf16)acc[mf][nf][r];
        *(uint2*)(o + (size_t)P * ldo + mb + m_l) = pk.u;
        if (mode == 2) {
          __bf16* o2 = (__bf16*)out2 + (size_t)z * oB;
#pragma unroll
          for (int r = 0; r < 4; ++r)
            o2[(size_t)(mb + m_l + r) * 1024 + P] = pk.h[r];
        }
      }
    }
  }
}

// ---------------- 3x3 conv on 32x32 images, implicit GEMM 128x128 ----------------
// in: [n][1024][CI] bf16 NHWC ; wp: [9][CO][CI] ; out: [n][1024][CO] bf16, bn+relu
template <int CI, int KCH>
__global__ __launch_bounds__(256, 2)
void conv3x3_32(const __bf16* __restrict__ in, const __bf16* __restrict__ wp,
                const float* __restrict__ sc, const float* __restrict__ bi,
                __bf16* __restrict__ out, const int CO) {
  __shared__ __align__(16) __bf16 tile[4 * 204 * 8];  // [kgrp][6*34 pix][8ci]
  __shared__ float s_sc[128], s_bi[128];
  const int tid = threadIdx.x;
  const int lane = tid & 63, wv = tid >> 6;
  const int ln = lane & 15, q = lane >> 4;
  const int pblk = blockIdx.x, cb = blockIdx.y;
  const int n = pblk >> 3, y0 = (pblk & 7) << 2;
  const int wm = wv >> 1, wn = wv & 1;

  if (tid < 128) { int c = cb * 128 + tid; s_sc[tid] = sc[c]; s_bi[tid] = bi[c]; }
  for (int t = tid; t < 816; t += 256) ((uint4*)tile)[t] = make_uint4(0, 0, 0, 0);

  v4f acc[4][4];
#pragma unroll
  for (int mf = 0; mf < 4; ++mf) {
#pragma unroll
    for (int nf = 0; nf < 4; ++nf) {
#pragma unroll
      for (int r = 0; r < 4; ++r) acc[mf][nf][r] = 0.f;
    }
  }
  const __bf16* pa[4];
#pragma unroll
  for (int mf = 0; mf < 4; ++mf) {
    int co = cb * 128 + wm * 64 + mf * 16 + ln;
    pa[mf] = wp + (size_t)co * CI + q * 8;
  }
  int pixb[4];
#pragma unroll
  for (int nf = 0; nf < 4; ++nf) {
    int n_l = wn * 64 + nf * 16 + ln;
    pixb[nf] = (n_l >> 5) * 34 + (n_l & 31);
  }
  const __bf16* inb = in + (size_t)n * 1024 * CI;
  __syncthreads();

  for (int kc = 0; kc < KCH; ++kc) {
    const int ci0 = kc * 32;
    if (lane < 32) {
#pragma unroll
      for (int t2 = 0; t2 < 6; ++t2) {
        int y = y0 - 1 + t2;
        if (y >= 0 && y < 32)
          g2l16(&tile[(wv * 204 + t2 * 34 + 1) * 8],
                inb + ((size_t)(y * 32 + lane) * CI + ci0 + wv * 8));
      }
    }
    __syncthreads();
#pragma unroll
    for (int tap = 0; tap < 9; ++tap) {
      const int ty = tap / 3, tx = tap % 3;
      v8bf bfr[4];
#pragma unroll
      for (int nf = 0; nf < 4; ++nf)
        bfr[nf] = *(const v8bf*)&tile[(q * 204 + pixb[nf] + ty * 34 + tx) * 8];
      const size_t toff = (size_t)tap * CO * CI + ci0;
#pragma unroll
      for (int mf = 0; mf < 4; ++mf) {
        v8bf af = *(const v8bf*)(pa[mf] + toff);
#pragma unroll
        for (int nf = 0; nf < 4; ++nf)
          acc[mf][nf] = MFMA16(af, bfr[nf], acc[mf][nf]);
      }
    }
    __syncthreads();
  }

#pragma unroll
  for (int mf = 0; mf < 4; ++mf) {
    const int m_l = wm * 64 + mf * 16 + q * 4;
#pragma unroll
    for (int nf = 0; nf < 4; ++nf) {
      const int n_l = wn * 64 + nf * 16 + ln;
      const int p_img = (y0 + (n_l >> 5)) * 32 + (n_l & 31);
      union { __bf16 h[4]; uint2 u; } pk;
#pragma unroll
      for (int r = 0; r < 4; ++r) {
        float v = acc[mf][nf][r] * s_sc[m_l + r] + s_bi[m_l + r];
        pk.h[r] = (__bf16)fmaxf(v, 0.f);
      }
      *(uint2*)(out + (size_t)(n * 1024 + p_img) * CO + cb * 128 + m_l) = pk.u;
    }
  }
}

// ---------------- conv4a: fused x8 bilinear upsample + 3x3 conv 512->256 ----------------
// y3: [n][1024][512] bf16 ; out y4: [n][256*256][256] bf16, bn4+relu
// Coarse 4x8-pixel footprint staged in LDS (double-buffered, global_load_lds);
// interp weights/offsets hoisted out of the K-loop; tile s-group stride padded
// 204->206 pixels to stagger LDS quarter bank bases (0/24/16/8).
__global__ __launch_bounds__(256, 2)
void conv4a_up(const __bf16* __restrict__ y3, const __bf16* __restrict__ wp,
               const float* __restrict__ sc, const float* __restrict__ bi,
               __bf16* __restrict__ out) {
  __shared__ __align__(16) __bf16 tile[4 * 206 * 8];
  __shared__ __align__(16) __bf16 coarse[2][1024];  // [buf][(cy*8+cx)*32 + s*8 + i]
  __shared__ float s_sc[128], s_bi[128];
  const int tid = threadIdx.x;
  const int lane = tid & 63, wv = tid >> 6;
  const int ln = lane & 15, q = lane >> 4;
  const int xblk = blockIdx.x;
  const int cb = blockIdx.y & 1, strip = blockIdx.y >> 1;
  const int n = blockIdx.z;
  const int oy0 = strip * 4, ox0 = xblk * 32;
  const int wm = wv >> 1, wn = wv & 1;

  if (tid < 128) { int c = cb * 128 + tid; s_sc[tid] = sc[c]; s_bi[tid] = bi[c]; }

  const int cyA = (oy0 >= 1) ? ((oy0 - 1) * 31) / 255 : 0;
  const int cxA = (ox0 >= 1) ? ((ox0 - 1) * 31) / 255 : 0;

  // hoisted per-thread interp state (thread tid<204 owns window pixel tid, all 4 ci-subgroups)
  int o00 = 0, dX = 0, dY = 0;
  float w00 = 0.f, w01 = 0.f, w10 = 0.f, w11 = 0.f;
  bool valid = false;
  if (tid < 204) {
    int rr = tid / 34, cc = tid - rr * 34;
    int fy = oy0 - 1 + rr, fx = ox0 - 1 + cc;
    if (fy >= 0 && fy <= 255 && fx >= 0 && fx <= 255) {
      valid = true;
      float syf = fy * (31.0f / 255.0f);
      int yy0 = (int)syf; float wy = syf - yy0;
      int yy1 = yy0 < 31 ? yy0 + 1 : 31;
      float sxf = fx * (31.0f / 255.0f);
      int xx0 = (int)sxf; float wx = sxf - xx0;
      int xx1 = xx0 < 31 ? xx0 + 1 : 31;
      o00 = ((yy0 - cyA) * 8 + (xx0 - cxA)) * 32;
      dX = (xx1 - xx0) * 32;
      dY = (yy1 - yy0) * 256;
      w00 = (1.f - wy) * (1.f - wx); w01 = (1.f - wy) * wx;
      w10 = wy * (1.f - wx);         w11 = wy * wx;
    }
  }

  v4f acc[4][4];
#pragma unroll
  for (int mf = 0; mf < 4; ++mf) {
#pragma unroll
    for (int nf = 0; nf < 4; ++nf) {
#pragma unroll
      for (int r = 0; r < 4; ++r) acc[mf][nf][r] = 0.f;
    }
  }
  const __bf16* pa[4];
#pragma unroll
  for (int mf = 0; mf < 4; ++mf) {
    int co = cb * 128 + wm * 64 + mf * 16 + ln;
    pa[mf] = wp + (size_t)co * 512 + q * 8;
  }
  int pixb[4];
#pragma unroll
  for (int nf = 0; nf < 4; ++nf) {
    int n_l = wn * 64 + nf * 16 + ln;
    pixb[nf] = (n_l >> 5) * 34 + (n_l & 31);
  }
  const __bf16* src = y3 + (size_t)n * 1024 * 512;

  // coarse staging lane mapping (first two waves; dest = wave-uniform base + lane*16)
  const int sp = tid >> 2, ss = tid & 3;
  const int scy = min(cyA + (sp >> 3), 31), scx = min(cxA + (sp & 7), 31);
  const size_t soff = (size_t)(scy * 32 + scx) * 512 + ss * 8;

  if (wv < 2) g2l16(&coarse[0][wv * 512], src + soff);
  __syncthreads();

  for (int kc = 0; kc < 16; ++kc) {
    const int ci0 = kc * 32;
    const int buf = kc & 1;
    if (kc < 15 && wv < 2)
      g2l16(&coarse[buf ^ 1][wv * 512], src + soff + ci0 + 32);
    if (tid < 204) {
      const __bf16* cbase = &coarse[buf][0];
      const int oA = o00, oB = o00 + dX, oC = o00 + dY, oD = o00 + dY + dX;
#pragma unroll
      for (int s = 0; s < 4; ++s) {
        v8bf val;
        if (valid) {
          v8bf a = *(const v8bf*)(cbase + oA + s * 8);
          v8bf b = *(const v8bf*)(cbase + oB + s * 8);
          v8bf c = *(const v8bf*)(cbase + oC + s * 8);
          v8bf d = *(const v8bf*)(cbase + oD + s * 8);
#pragma unroll
          for (int i = 0; i < 8; ++i)
            val[i] = (__bf16)(w00 * (float)a[i] + w01 * (float)b[i] +
                              w10 * (float)c[i] + w11 * (float)d[i]);
        } else {
#pragma unroll
          for (int i = 0; i < 8; ++i) val[i] = (__bf16)0.f;
        }
        *(v8bf*)&tile[(s * 206 + tid) * 8] = val;
      }
    }
    __syncthreads();
#pragma unroll
    for (int tap = 0; tap < 9; ++tap) {
      const int ty = tap / 3, tx = tap % 3;
      v8bf bfr[4];
#pragma unroll
      for (int nf = 0; nf < 4; ++nf)
        bfr[nf] = *(const v8bf*)&tile[(q * 206 + pixb[nf] + ty * 34 + tx) * 8];
      const size_t toff = (size_t)tap * 256 * 512 + ci0;
#pragma unroll
      for (int mf = 0; mf < 4; ++mf) {
        v8bf af = *(const v8bf*)(pa[mf] + toff);
#pragma unroll
        for (int nf = 0; nf < 4; ++nf)
          acc[mf][nf] = MFMA16(af, bfr[nf], acc[mf][nf]);
      }
    }
    __syncthreads();
  }

#pragma unroll
  for (int mf = 0; mf < 4; ++mf) {
    const int m_l = wm * 64 + mf * 16 + q * 4;
#pragma unroll
    for (int nf = 0; nf < 4; ++nf) {
      const int n_l = wn * 64 + nf * 16 + ln;
      const int oy = oy0 + (n_l >> 5), ox = ox0 + (n_l & 31);
      union { __bf16 h[4]; uint2 u; } pk;
#pragma unroll
      for (int r = 0; r < 4; ++r) {
        float v = acc[mf][nf][r] * s_sc[m_l + r] + s_bi[m_l + r];
        pk.h[r] = (__bf16)fmaxf(v, 0.f);
      }
      *(uint2*)(out + ((size_t)n * 65536 + (size_t)oy * 256 + ox) * 256 + cb * 128 + m_l) = pk.u;
    }
  }
}

// ---------------- conv4b: 3x3 conv 256->19 on 256x256, fp32 NCHW out ----------------
__global__ __launch_bounds__(256, 2)
void conv4b_k(const __bf16* __restrict__ y4, const __bf16* __restrict__ wp,
              float* __restrict__ outp) {
  __shared__ __align__(16) __bf16 tile[4 * 204 * 8];
  const int tid = threadIdx.x;
  const int lane = tid & 63, wv = tid >> 6;
  const int ln = lane & 15, q = lane >> 4;
  const int xblk = blockIdx.x, strip = blockIdx.y, n = blockIdx.z;
  const int oy0 = strip * 4, ox0 = xblk * 32;

  for (int t = tid; t < 816; t += 256) ((uint4*)tile)[t] = make_uint4(0, 0, 0, 0);

  v4f acc[2][2];
#pragma unroll
  for (int mf = 0; mf < 2; ++mf) {
#pragma unroll
    for (int nf = 0; nf < 2; ++nf) {
#pragma unroll
      for (int r = 0; r < 4; ++r) acc[mf][nf][r] = 0.f;
    }
  }
  const __bf16* pa[2];
#pragma unroll
  for (int mf = 0; mf < 2; ++mf)
    pa[mf] = wp + (size_t)(mf * 16 + ln) * 256 + q * 8;
  int pixb[2];
#pragma unroll
  for (int nf = 0; nf < 2; ++nf) {
    int n_l = wv * 32 + nf * 16 + ln;
    pixb[nf] = (n_l >> 5) * 34 + (n_l & 31);
  }
  const __bf16* src = y4 + (size_t)n * 65536 * 256;
  __syncthreads();

  for (int kc = 0; kc < 8; ++kc) {
    const int ci0 = kc * 32;
#pragma unroll
    for (int t2 = 0; t2 < 6; ++t2) {
      int y = oy0 - 1 + t2;
      int gx = ox0 - 1 + lane;
      if (y >= 0 && y < 256 && lane < 34 && gx >= 0 && gx < 256)
        g2l16(&tile[(wv * 204 + t2 * 34) * 8],
              src + ((size_t)(y * 256 + gx) * 256 + ci0 + wv * 8));
    }
    __syncthreads();
#pragma unroll
    for (int tap = 0; tap < 9; ++tap) {
      const int ty = tap / 3, tx = tap % 3;
      v8bf bfr[2];
#pragma unroll
      for (int nf = 0; nf < 2; ++nf)
        bfr[nf] = *(const v8bf*)&tile[(q * 204 + pixb[nf] + ty * 34 + tx) * 8];
      const size_t toff = (size_t)tap * 32 * 256 + ci0;
#pragma unroll
      for (int mf = 0; mf < 2; ++mf) {
        v8bf af = *(const v8bf*)(pa[mf] + toff);
#pragma unroll
        for (int nf = 0; nf < 2; ++nf)
          acc[mf][nf] = MFMA16(af, bfr[nf], acc[mf][nf]);
      }
    }
    __syncthreads();
  }

#pragma unroll
  for (int mf = 0; mf < 2; ++mf) {
    const int m_l = mf * 16 + q * 4;
#pragma unroll
    for (int nf = 0; nf < 2; ++nf) {
      const int n_l = wv * 32 + nf * 16 + ln;
      const int oy = oy0 + (n_l >> 5), ox = ox0 + (n_l & 31);
#pragma unroll
      for (int r = 0; r < 4; ++r) {
        int co = m_l + r;
        if (co < 19)
          outp[(((size_t)n * 19 + co) * 256 + oy) * 256 + ox] = acc[mf][nf][r];
      }
    }
  }
}

// ---------------- softmax kernels ----------------

__global__ void softmax1024(const float* __restrict__ S, __bf16* __restrict__ O) {
  __shared__ float red[256];
  const int row = blockIdx.x, tid = threadIdx.x;
  const float* p = S + (size_t)row * 1024;
  float v0 = p[tid], v1 = p[tid + 256], v2 = p[tid + 512], v3 = p[tid + 768];
  float m = fmaxf(fmaxf(v0, v1), fmaxf(v2, v3));
  red[tid] = m; __syncthreads();
  for (int s = 128; s > 0; s >>= 1) { if (tid < s) red[tid] = fmaxf(red[tid], red[tid + s]); __syncthreads(); }
  m = red[0]; __syncthreads();
  v0 = __expf(v0 - m); v1 = __expf(v1 - m); v2 = __expf(v2 - m); v3 = __expf(v3 - m);
  red[tid] = v0 + v1 + v2 + v3; __syncthreads();
  for (int s = 128; s > 0; s >>= 1) { if (tid < s) red[tid] += red[tid + s]; __syncthreads(); }
  float inv = 1.0f / red[0];
  __bf16* o = O + (size_t)row * 1024;
  o[tid] = (__bf16)(v0 * inv); o[tid + 256] = (__bf16)(v1 * inv);
  o[tid + 512] = (__bf16)(v2 * inv); o[tid + 768] = (__bf16)(v3 * inv);
}

// softmax rows of Scc[c][d] (512 wide), writes transposed: O[d*512+c] = Asm[c][d]
__global__ void softmaxT512(const float* __restrict__ S, __bf16* __restrict__ O) {
  __shared__ float red[256];
  const int row = blockIdx.x, tid = threadIdx.x;
  const float* p = S + (size_t)row * 512;
  float v0 = p[tid], v1 = p[tid + 256];
  float m = fmaxf(v0, v1);
  red[tid] = m; __syncthreads();
  for (int s = 128; s > 0; s >>= 1) { if (tid < s) red[tid] = fmaxf(red[tid], red[tid + s]); __syncthreads(); }
  m = red[0]; __syncthreads();
  v0 = __expf(v0 - m); v1 = __expf(v1 - m);
  red[tid] = v0 + v1; __syncthreads();
  for (int s = 128; s > 0; s >>= 1) { if (tid < s) red[tid] += red[tid + s]; __syncthreads(); }
  float inv = 1.0f / red[0];
  int n = row >> 9, c = row & 511;
  __bf16* o = O + (size_t)n * 262144 + c;
  o[(size_t)tid * 512] = (__bf16)(v0 * inv);
  o[(size_t)(tid + 256) * 512] = (__bf16)(v1 * inv);
}

// z = y1 + y2 + gamma*E + beta*X  (all [n*1024][512]-ish)
__global__ void combine_z(const __bf16* __restrict__ y12, const __bf16* __restrict__ E,
                          const __bf16* __restrict__ X, const float* __restrict__ gp,
                          const float* __restrict__ bp, __bf16* __restrict__ z) {
  size_t i = (size_t)blockIdx.x * 256 + threadIdx.x;
  int pg = (int)(i >> 9), c = (int)(i & 511);
  float g = gp[0], b = bp[0];
  float v = (float)y12[(size_t)pg * 1024 + c] + (float)y12[(size_t)pg * 1024 + 512 + c] +
            g * (float)E[i] + b * (float)X[i];
  z[i] = (__bf16)v;
}

// ---------------- launcher ----------------

extern "C" void kernel_launch(void* const* d_in, const int* in_sizes, int n_in,
                              void* d_out, int out_size, void* d_ws, size_t ws_size,
                              hipStream_t stream) {
  const float* x    = (const float*)d_in[0];
  const float* w1   = (const float*)d_in[1];
  const float* bn1g = (const float*)d_in[2];
  const float* bn1b = (const float*)d_in[3];
  const float* bn1m = (const float*)d_in[4];
  const float* bn1v = (const float*)d_in[5];
  const float* w2   = (const float*)d_in[6];
  const float* bn2g = (const float*)d_in[7];
  const float* bn2b = (const float*)d_in[8];
  const float* bn2m = (const float*)d_in[9];
  const float* bn2v = (const float*)d_in[10];
  const float* wB   = (const float*)d_in[11];
  const float* gam  = (const float*)d_in[12];
  const float* bet  = (const float*)d_in[13];
  const float* w3   = (const float*)d_in[14];
  const float* bn3g = (const float*)d_in[15];
  const float* bn3b = (const float*)d_in[16];
  const float* bn3m = (const float*)d_in[17];
  const float* bn3v = (const float*)d_in[18];
  const float* w4a  = (const float*)d_in[19];
  const float* bn4g = (const float*)d_in[20];
  const float* bn4b = (const float*)d_in[21];
  const float* bn4m = (const float*)d_in[22];
  const float* bn4v = (const float*)d_in[23];
  const float* w4b  = (const float*)d_in[24];

  char* ws = (char*)d_ws;
  size_t off = 0;
  auto take = [&](size_t bytes) -> char* {
    char* p = ws + off;
    off += (bytes + 255) & ~(size_t)255;
    return p;
  };
  __bf16* w12b  = (__bf16*)take(9ULL * 1024 * 2048 * 2);
  __bf16* w3b   = (__bf16*)take(9ULL * 512 * 512 * 2);
  __bf16* w4ab  = (__bf16*)take(9ULL * 256 * 512 * 2);
  __bf16* w4bb  = (__bf16*)take(9ULL * 32 * 256 * 2);
  __bf16* wBb   = (__bf16*)take(512ULL * 512 * 2);
  float*  sc12  = (float*)take(1024 * 4);
  float*  bi12  = (float*)take(1024 * 4);
  float*  sc3   = (float*)take(512 * 4);
  float*  bi3   = (float*)take(512 * 4);
  float*  sc4   = (float*)take(256 * 4);
  float*  bi4   = (float*)take(256 * 4);
  __bf16* xb    = (__bf16*)take(4ULL * 1024 * 2048 * 2);
  __bf16* y12   = (__bf16*)take(4ULL * 1024 * 1024 * 2);
  __bf16* Bm_pc = (__bf16*)take(4ULL * 1024 * 512 * 2);
  __bf16* Bm_cp = (__bf16*)take(4ULL * 512 * 1024 * 2);
  float*  Smat  = (float*)take(4ULL * 1024 * 1024 * 4);
  __bf16* Ssm   = (__bf16*)take(4ULL * 1024 * 1024 * 2);
  __bf16* E_pc  = (__bf16*)take(4ULL * 1024 * 512 * 2);
  __bf16* y2t   = (__bf16*)take(4ULL * 512 * 1024 * 2);
  float*  Scc   = (float*)take(4ULL * 512 * 512 * 4);
  __bf16* AsmT  = (__bf16*)take(4ULL * 512 * 512 * 2);
  __bf16* X_pc  = (__bf16*)take(4ULL * 1024 * 512 * 2);
  __bf16* zb    = (__bf16*)take(4ULL * 1024 * 512 * 2);
  __bf16* y4    = (__bf16*)take(4ULL * 65536 * 256 * 2);
  __bf16* y3    = (__bf16*)take(4ULL * 1024 * 512 * 2);

  // prep
  bnprep<<<2, 256, 0, stream>>>(bn1g, bn1b, bn1m, bn1v, sc12, bi12, 512);
  bnprep<<<2, 256, 0, stream>>>(bn2g, bn2b, bn2m, bn2v, sc12 + 512, bi12 + 512, 512);
  bnprep<<<2, 256, 0, stream>>>(bn3g, bn3b, bn3m, bn3v, sc3, bi3, 512);
  bnprep<<<1, 256, 0, stream>>>(bn4g, bn4b, bn4m, bn4v, sc4, bi4, 256);
  pack_w<<<4096, 256, 0, stream>>>(w1, w12b, 512, 512, 0, 1024, 2048, 9);
  pack_w<<<4096, 256, 0, stream>>>(w2, w12b, 512, 512, 512, 1024, 2048, 9);
  pack_w<<<1024, 256, 0, stream>>>(w3, w3b, 512, 512, 0, 512, 512, 9);
  pack_w<<<512, 256, 0, stream>>>(w4a, w4ab, 256, 256, 0, 256, 512, 9);
  pack_w<<<32, 256, 0, stream>>>(w4b, w4bb, 32, 19, 0, 32, 256, 9);
  pack_w<<<1024, 256, 0, stream>>>(wB, wBb, 512, 512, 0, 512, 512, 1);
  cast_x_k<<<dim3(16, 32, 4), 256, 0, stream>>>(x, xb);

  // conv1 + conv2 fused as one GEMM (co 0..511 = conv1, 512..1023 = conv2)
  conv3x3_32<2048, 64><<<dim3(32, 8), 256, 0, stream>>>(xb, w12b, sc12, bi12, y12, 1024);

  // position attention
  gemm_nt<<<dim3(8, 4, 4), 256, 0, stream>>>(wBb, y12, 0, 1048576, 512, 1024, 16, 2,
                                             Bm_pc, Bm_cp, 524288, 512);
  gemm_nt<<<dim3(8, 8, 4), 256, 0, stream>>>(Bm_pc, Bm_pc, 524288, 524288, 512, 512, 16, 1,
                                             Smat, nullptr, 1048576, 1024);
  softmax1024<<<4096, 256, 0, stream>>>(Smat, Ssm);
  gemm_nt<<<dim3(8, 4, 4), 256, 0, stream>>>(Bm_cp, Ssm, 524288, 1048576, 1024, 1024, 32, 0,
                                             E_pc, nullptr, 524288, 512);

  // channel attention
  trans_y2<<<dim3(16, 8, 4), 256, 0, stream>>>(y12, y2t);
  gemm_nt<<<dim3(4, 4, 4), 256, 0, stream>>>(y2t, y2t, 524288, 524288, 1024, 1024, 32, 1,
                                             Scc, nullptr, 262144, 512);
  softmaxT512<<<2048, 256, 0, stream>>>(Scc, AsmT);
  gemm_nt<<<dim3(8, 4, 4), 256, 0, stream>>>(AsmT, y12 + 512, 262144, 1048576, 512, 1024, 16, 0,
                                             X_pc, nullptr, 524288, 512);

  // z = pa + ca
  combine_z<<<8192, 256, 0, stream>>>(y12, E_pc, X_pc, gam, bet, zb);

  // conv3
  conv3x3_32<512, 16><<<dim3(32, 4), 256, 0, stream>>>(zb, w3b, sc3, bi3, y3, 512);

  // conv4a fused with x8 bilinear upsample
  conv4a_up<<<dim3(8, 128, 4), 256, 0, stream>>>(y3, w4ab, sc4, bi4, y4);

  // conv4b -> d_out (fp32 NCHW)
  conv4b_k<<<dim3(8, 64, 4), 256, 0, stream>>>(y4, w4bb, (float*)d_out);
}

// Round 3
// 2110.860 us; speedup vs baseline: 1.0657x; 1.0105x over previous
//
#include <hip/hip_runtime.h>
#include <stdint.h>

typedef __bf16 v8bf __attribute__((ext_vector_type(8)));
typedef float  v4f  __attribute__((ext_vector_type(4)));

#define MFMA16(a,b,c) __builtin_amdgcn_mfma_f32_16x16x32_bf16((a),(b),(c),0,0,0)

__device__ __forceinline__ void g2l16(void* lds, const void* g) {
  __builtin_amdgcn_global_load_lds(
      (__attribute__((address_space(1))) unsigned int*)g,
      (__attribute__((address_space(3))) unsigned int*)lds, 16, 0, 0);
}

// ---------------- small prep kernels ----------------

__global__ void bnprep(const float* __restrict__ g, const float* __restrict__ b,
                       const float* __restrict__ m, const float* __restrict__ v,
                       float* __restrict__ sc, float* __restrict__ bi, int C) {
  int i = blockIdx.x * 256 + threadIdx.x;
  if (i < C) {
    float s = g[i] * rsqrtf(v[i] + 1e-5f);
    sc[i] = s;
    bi[i] = b[i] - m[i] * s;
  }
}

// OIHW fp32 -> [tap][co][ci] bf16 (co may be zero-padded)
__global__ void pack_w(const float* __restrict__ src, __bf16* __restrict__ dst,
                       int co_cnt, int co_src, int co_off, int co_tot, int ci, int taps) {
  int idx = blockIdx.x * 256 + threadIdx.x;
  if (idx >= co_cnt * ci) return;
  int c = idx % ci, co = idx / ci;
  for (int t = 0; t < taps; ++t) {
    float v = (co < co_src) ? src[((size_t)co * ci + c) * taps + t] : 0.f;
    dst[((size_t)t * co_tot + co_off + co) * ci + c] = (__bf16)v;
  }
}

// x NCHW fp32 -> xb [n][p][2048] bf16
__global__ void cast_x_k(const float* __restrict__ x, __bf16* __restrict__ xb) {
  __shared__ float tl[64][65];
  int p0 = blockIdx.x * 64, c0 = blockIdx.y * 64, n = blockIdx.z;
  const float* xin = x + (size_t)n * 2048 * 1024;
  for (int it = 0; it < 16; ++it) {
    int idx = it * 256 + threadIdx.x;
    int px = idx & 63, cl = idx >> 6;
    tl[px][cl] = xin[(size_t)(c0 + cl) * 1024 + p0 + px];
  }
  __syncthreads();
  for (int it = 0; it < 16; ++it) {
    int idx = it * 256 + threadIdx.x;
    int cl = idx & 63, px = idx >> 6;
    xb[((size_t)n * 1024 + p0 + px) * 2048 + c0 + cl] = (__bf16)tl[px][cl];
  }
}

// y12[:,512:1024] ([n][p][1024]) -> y2t [n][c][p] bf16
__global__ void trans_y2(const __bf16* __restrict__ y12, __bf16* __restrict__ y2t) {
  __shared__ __bf16 tl[64][72];
  int p0 = blockIdx.x * 64, c0 = blockIdx.y * 64, n = blockIdx.z;
  for (int it = 0; it < 16; ++it) {
    int idx = it * 256 + threadIdx.x;
    int cl = idx & 63, px = idx >> 6;
    tl[px][cl] = y12[((size_t)n * 1024 + p0 + px) * 1024 + 512 + c0 + cl];
  }
  __syncthreads();
  for (int it = 0; it < 16; ++it) {
    int idx = it * 256 + threadIdx.x;
    int px = idx & 63, cl = idx >> 6;
    y2t[((size_t)n * 512 + c0 + cl) * 1024 + p0 + px] = tl[px][cl];
  }
}

// ---------------- generic 128x128 GEMM, single-barrier double-buffered ----------------
// D[m][n] = sum_k A[m][k]*B[n][k]
// mode 0: bf16 out[P*ldo + m]; mode 1: f32 out[m*ldo + P]; mode 2: mode0 + bf16 out2[m*1024 + P]
__global__ __launch_bounds__(256, 2)
void gemm_nt(const __bf16* __restrict__ A, const __bf16* __restrict__ B,
             size_t aB, size_t bB, int lda, int ldb, int kch, int mode,
             void* __restrict__ out, void* __restrict__ out2, size_t oB, int ldo) {
  __shared__ __align__(16) __bf16 tile[2][4 * 128 * 8];
  const int tid = threadIdx.x;
  const int lane = tid & 63, wv = tid >> 6;
  const int ln = lane & 15, q = lane >> 4;
  const int wm = wv >> 1, wn = wv & 1;
  const int p0 = blockIdx.x * 128, mb = blockIdx.y * 128, z = blockIdx.z;
  A += (size_t)z * aB; B += (size_t)z * bB;

  v4f acc[4][4];
#pragma unroll
  for (int mf = 0; mf < 4; ++mf)
#pragma unroll
    for (int nf = 0; nf < 4; ++nf)
#pragma unroll
      for (int r = 0; r < 4; ++r) acc[mf][nf][r] = 0.f;

  const __bf16* pa[4];
#pragma unroll
  for (int mf = 0; mf < 4; ++mf)
    pa[mf] = A + (size_t)(mb + wm * 64 + mf * 16 + ln) * lda + q * 8;

  // stage chunk 0 -> buf 0
#pragma unroll
  for (int t2 = 0; t2 < 2; ++t2)
    g2l16(&tile[0][(wv * 128 + t2 * 64) * 8],
          B + (size_t)(p0 + t2 * 64 + lane) * ldb + wv * 8);
  __syncthreads();

  for (int kc = 0; kc < kch; ++kc) {
    const int tb = kc & 1;
    if (kc + 1 < kch) {
      const int c1 = (kc + 1) * 32;
#pragma unroll
      for (int t2 = 0; t2 < 2; ++t2)
        g2l16(&tile[tb ^ 1][(wv * 128 + t2 * 64) * 8],
              B + (size_t)(p0 + t2 * 64 + lane) * ldb + c1 + wv * 8);
    }
    const int c0 = kc * 32;
    v8bf bfr[4];
#pragma unroll
    for (int nf = 0; nf < 4; ++nf)
      bfr[nf] = *(const v8bf*)&tile[tb][(q * 128 + wn * 64 + nf * 16 + ln) * 8];
#pragma unroll
    for (int mf = 0; mf < 4; ++mf) {
      v8bf af = *(const v8bf*)(pa[mf] + c0);
#pragma unroll
      for (int nf = 0; nf < 4; ++nf)
        acc[mf][nf] = MFMA16(af, bfr[nf], acc[mf][nf]);
    }
    __syncthreads();
  }

#pragma unroll
  for (int mf = 0; mf < 4; ++mf) {
    const int m_l = wm * 64 + mf * 16 + q * 4;
#pragma unroll
    for (int nf = 0; nf < 4; ++nf) {
      const int n_l = wn * 64 + nf * 16 + ln;
      const int P = p0 + n_l;
      if (mode == 1) {
        float* o = (float*)out + (size_t)z * oB;
#pragma unroll
        for (int r = 0; r < 4; ++r)
          o[(size_t)(mb + m_l + r) * ldo + P] = acc[mf][nf][r];
      } else {
        __bf16* o = (__bf16*)out + (size_t)z * oB;
        union { __bf16 h[4]; uint2 u; } pk;
#pragma unroll
        for (int r = 0; r < 4; ++r) pk.h[r] = (__bf16)acc[mf][nf][r];
        *(uint2*)(o + (size_t)P * ldo + mb + m_l) = pk.u;
        if (mode == 2) {
          __bf16* o2 = (__bf16*)out2 + (size_t)z * oB;
#pragma unroll
          for (int r = 0; r < 4; ++r)
            o2[(size_t)(mb + m_l + r) * 1024 + P] = pk.h[r];
        }
      }
    }
  }
}

// ---------------- 3x3 conv on 32x32 images, single-barrier double-buffered ----------------
// in: [n][1024][CI] bf16 NHWC ; wp: [9][CO][CI] ; out: [n][1024][CO] bf16, bn+relu
template <int CI, int KCH>
__global__ __launch_bounds__(256, 2)
void conv3x3_32(const __bf16* __restrict__ in, const __bf16* __restrict__ wp,
                const float* __restrict__ sc, const float* __restrict__ bi,
                __bf16* __restrict__ out, const int CO) {
  __shared__ __align__(16) __bf16 tile[2][816 * 8];  // [buf][kgrp*204 + pix][8ci]
  __shared__ float s_sc[128], s_bi[128];
  const int tid = threadIdx.x;
  const int lane = tid & 63, wv = tid >> 6;
  const int ln = lane & 15, q = lane >> 4;
  const int pblk = blockIdx.x, cb = blockIdx.y;
  const int n = pblk >> 3, y0 = (pblk & 7) << 2;
  const int wm = wv >> 1, wn = wv & 1;

  if (tid < 128) { int c = cb * 128 + tid; s_sc[tid] = sc[c]; s_bi[tid] = bi[c]; }
  for (int t = tid; t < 1632; t += 256) ((uint4*)tile)[t] = make_uint4(0, 0, 0, 0);

  v4f acc[4][4];
#pragma unroll
  for (int mf = 0; mf < 4; ++mf)
#pragma unroll
    for (int nf = 0; nf < 4; ++nf)
#pragma unroll
      for (int r = 0; r < 4; ++r) acc[mf][nf][r] = 0.f;

  const __bf16* pa[4];
#pragma unroll
  for (int mf = 0; mf < 4; ++mf) {
    int co = cb * 128 + wm * 64 + mf * 16 + ln;
    pa[mf] = wp + (size_t)co * CI + q * 8;
  }
  int pixb[4];
#pragma unroll
  for (int nf = 0; nf < 4; ++nf) {
    int n_l = wn * 64 + nf * 16 + ln;
    pixb[nf] = (n_l >> 5) * 34 + (n_l & 31);
  }
  const __bf16* inb = in + (size_t)n * 1024 * CI;
  __syncthreads();  // zero-init visible before first g2l lands

  // stage chunk 0 -> buf 0
  if (lane < 32) {
#pragma unroll
    for (int t2 = 0; t2 < 6; ++t2) {
      int y = y0 - 1 + t2;
      if (y >= 0 && y < 32)
        g2l16(&tile[0][(wv * 204 + t2 * 34 + 1) * 8],
              inb + ((size_t)(y * 32 + lane) * CI + wv * 8));
    }
  }
  __syncthreads();

  for (int kc = 0; kc < KCH; ++kc) {
    const int tb = kc & 1;
    if (kc + 1 < KCH && lane < 32) {
      const int c1 = (kc + 1) * 32;
#pragma unroll
      for (int t2 = 0; t2 < 6; ++t2) {
        int y = y0 - 1 + t2;
        if (y >= 0 && y < 32)
          g2l16(&tile[tb ^ 1][(wv * 204 + t2 * 34 + 1) * 8],
                inb + ((size_t)(y * 32 + lane) * CI + c1 + wv * 8));
      }
    }
    const int ci0 = kc * 32;
#pragma unroll
    for (int tap = 0; tap < 9; ++tap) {
      const int ty = tap / 3, tx = tap % 3;
      v8bf bfr[4];
#pragma unroll
      for (int nf = 0; nf < 4; ++nf)
        bfr[nf] = *(const v8bf*)&tile[tb][(q * 204 + pixb[nf] + ty * 34 + tx) * 8];
      const size_t toff = (size_t)tap * CO * CI + ci0;
#pragma unroll
      for (int mf = 0; mf < 4; ++mf) {
        v8bf af = *(const v8bf*)(pa[mf] + toff);
#pragma unroll
        for (int nf = 0; nf < 4; ++nf)
          acc[mf][nf] = MFMA16(af, bfr[nf], acc[mf][nf]);
      }
    }
    __syncthreads();
  }

#pragma unroll
  for (int mf = 0; mf < 4; ++mf) {
    const int m_l = wm * 64 + mf * 16 + q * 4;
#pragma unroll
    for (int nf = 0; nf < 4; ++nf) {
      const int n_l = wn * 64 + nf * 16 + ln;
      const int p_img = (y0 + (n_l >> 5)) * 32 + (n_l & 31);
      union { __bf16 h[4]; uint2 u; } pk;
#pragma unroll
      for (int r = 0; r < 4; ++r) {
        float v = acc[mf][nf][r] * s_sc[m_l + r] + s_bi[m_l + r];
        pk.h[r] = (__bf16)fmaxf(v, 0.f);
      }
      *(uint2*)(out + (size_t)(n * 1024 + p_img) * CO + cb * 128 + m_l) = pk.u;
    }
  }
}

// ---------------- conv4a: fused x8 bilinear upsample + 3x3 conv 512->256 ----------------
// y3: [n][1024][512] bf16 ; out y4: [n][256*256][256] bf16, bn4+relu
// Single barrier per kc: g2l(kc+2) -> MFMA(tile[b]) -> expand(kc+1 -> tile[b^1]) -> barrier.
// coarse layout [buf][s][32pix][8ci] (16B pixel stride -> conflict-free expand reads).
__global__ __launch_bounds__(256, 2)
void conv4a_up(const __bf16* __restrict__ y3, const __bf16* __restrict__ wp,
               const float* __restrict__ sc, const float* __restrict__ bi,
               __bf16* __restrict__ out) {
  __shared__ __align__(16) __bf16 tile[2][4 * 206 * 8];
  __shared__ __align__(16) __bf16 coarse[2][1024];
  __shared__ float s_sc[128], s_bi[128];
  const int tid = threadIdx.x;
  const int lane = tid & 63, wv = tid >> 6;
  const int ln = lane & 15, q = lane >> 4;
  const int xblk = blockIdx.x;
  const int cb = blockIdx.y & 1, strip = blockIdx.y >> 1;
  const int n = blockIdx.z;
  const int oy0 = strip * 4, ox0 = xblk * 32;
  const int wm = wv >> 1, wn = wv & 1;

  if (tid < 128) { int c = cb * 128 + tid; s_sc[tid] = sc[c]; s_bi[tid] = bi[c]; }

  const int cyA = (oy0 >= 1) ? ((oy0 - 1) * 31) / 255 : 0;
  const int cxA = (ox0 >= 1) ? ((ox0 - 1) * 31) / 255 : 0;

  // hoisted per-thread interp state (pixel-index offsets into a [32pix][8ci] s-plane)
  int o00 = 0, dX = 0, dY = 0;
  float w00 = 0.f, w01 = 0.f, w10 = 0.f, w11 = 0.f;
  bool valid = false;
  if (tid < 204) {
    int rr = tid / 34, cc = tid - rr * 34;
    int fy = oy0 - 1 + rr, fx = ox0 - 1 + cc;
    if (fy >= 0 && fy <= 255 && fx >= 0 && fx <= 255) {
      valid = true;
      float syf = fy * (31.0f / 255.0f);
      int yy0 = (int)syf; float wy = syf - yy0;
      int yy1 = yy0 < 31 ? yy0 + 1 : 31;
      float sxf = fx * (31.0f / 255.0f);
      int xx0 = (int)sxf; float wx = sxf - xx0;
      int xx1 = xx0 < 31 ? xx0 + 1 : 31;
      o00 = (yy0 - cyA) * 8 + (xx0 - cxA);
      dX = xx1 - xx0;
      dY = (yy1 - yy0) * 8;
      w00 = (1.f - wy) * (1.f - wx); w01 = (1.f - wy) * wx;
      w10 = wy * (1.f - wx);         w11 = wy * wx;
    }
  }

  v4f acc[4][4];
#pragma unroll
  for (int mf = 0; mf < 4; ++mf)
#pragma unroll
    for (int nf = 0; nf < 4; ++nf)
#pragma unroll
      for (int r = 0; r < 4; ++r) acc[mf][nf][r] = 0.f;

  const __bf16* pa[4];
#pragma unroll
  for (int mf = 0; mf < 4; ++mf) {
    int co = cb * 128 + wm * 64 + mf * 16 + ln;
    pa[mf] = wp + (size_t)co * 512 + q * 8;
  }
  int pixb[4];
#pragma unroll
  for (int nf = 0; nf < 4; ++nf) {
    int n_l = wn * 64 + nf * 16 + ln;
    pixb[nf] = (n_l >> 5) * 34 + (n_l & 31);
  }
  const __bf16* src = y3 + (size_t)n * 1024 * 512;

  // staging mapping (2 waves, 128 lanes): s = tid>>5, pix = tid&31, dest = base + lane*16
  const int ssp = tid >> 5, spx = tid & 31;
  const int scy = min(cyA + (spx >> 3), 31), scx = min(cxA + (spx & 7), 31);
  const size_t soff = (size_t)(scy * 32 + scx) * 512 + ssp * 8;

  // prologue: coarse chunk0 -> cbuf0; expand chunk0 -> tile0; coarse chunk1 -> cbuf1
  if (wv < 2) g2l16(&coarse[0][wv * 512], src + soff);
  __syncthreads();
  if (tid < 204) {
    const __bf16* cb_ = coarse[0];
#pragma unroll
    for (int s = 0; s < 4; ++s) {
      v8bf val;
      if (valid) {
        const __bf16* base = cb_ + s * 256;
        v8bf a = *(const v8bf*)(base + o00 * 8);
        v8bf b = *(const v8bf*)(base + (o00 + dX) * 8);
        v8bf c = *(const v8bf*)(base + (o00 + dY) * 8);
        v8bf d = *(const v8bf*)(base + (o00 + dY + dX) * 8);
#pragma unroll
        for (int i = 0; i < 8; ++i)
          val[i] = (__bf16)(w00 * (float)a[i] + w01 * (float)b[i] +
                            w10 * (float)c[i] + w11 * (float)d[i]);
      } else {
#pragma unroll
        for (int i = 0; i < 8; ++i) val[i] = (__bf16)0.f;
      }
      *(v8bf*)&tile[0][(s * 206 + tid) * 8] = val;
    }
  }
  if (wv < 2) g2l16(&coarse[1][wv * 512], src + soff + 32);
  __syncthreads();

  for (int kc = 0; kc < 16; ++kc) {
    const int tb = kc & 1;
    if (kc < 14 && wv < 2)
      g2l16(&coarse[tb][wv * 512], src + soff + (kc + 2) * 32);
    // MFMA over chunk kc
    const int ci0 = kc * 32;
#pragma unroll
    for (int tap = 0; tap < 9; ++tap) {
      const int ty = tap / 3, tx = tap % 3;
      v8bf bfr[4];
#pragma unroll
      for (int nf = 0; nf < 4; ++nf)
        bfr[nf] = *(const v8bf*)&tile[tb][(q * 206 + pixb[nf] + ty * 34 + tx) * 8];
      const size_t toff = (size_t)tap * 256 * 512 + ci0;
#pragma unroll
      for (int mf = 0; mf < 4; ++mf) {
        v8bf af = *(const v8bf*)(pa[mf] + toff);
#pragma unroll
        for (int nf = 0; nf < 4; ++nf)
          acc[mf][nf] = MFMA16(af, bfr[nf], acc[mf][nf]);
      }
    }
    // expand chunk kc+1 -> tile[tb^1]
    if (kc < 15 && tid < 204) {
      const __bf16* cb_ = coarse[tb ^ 1];
#pragma unroll
      for (int s = 0; s < 4; ++s) {
        v8bf val;
        if (valid) {
          const __bf16* base = cb_ + s * 256;
          v8bf a = *(const v8bf*)(base + o00 * 8);
          v8bf b = *(const v8bf*)(base + (o00 + dX) * 8);
          v8bf c = *(const v8bf*)(base + (o00 + dY) * 8);
          v8bf d = *(const v8bf*)(base + (o00 + dY + dX) * 8);
#pragma unroll
          for (int i = 0; i < 8; ++i)
            val[i] = (__bf16)(w00 * (float)a[i] + w01 * (float)b[i] +
                              w10 * (float)c[i] + w11 * (float)d[i]);
        } else {
#pragma unroll
          for (int i = 0; i < 8; ++i) val[i] = (__bf16)0.f;
        }
        *(v8bf*)&tile[tb ^ 1][(s * 206 + tid) * 8] = val;
      }
    }
    __syncthreads();
  }

#pragma unroll
  for (int mf = 0; mf < 4; ++mf) {
    const int m_l = wm * 64 + mf * 16 + q * 4;
#pragma unroll
    for (int nf = 0; nf < 4; ++nf) {
      const int n_l = wn * 64 + nf * 16 + ln;
      const int oy = oy0 + (n_l >> 5), ox = ox0 + (n_l & 31);
      union { __bf16 h[4]; uint2 u; } pk;
#pragma unroll
      for (int r = 0; r < 4; ++r) {
        float v = acc[mf][nf][r] * s_sc[m_l + r] + s_bi[m_l + r];
        pk.h[r] = (__bf16)fmaxf(v, 0.f);
      }
      *(uint2*)(out + ((size_t)n * 65536 + (size_t)oy * 256 + ox) * 256 + cb * 128 + m_l) = pk.u;
    }
  }
}

// ---------------- conv4b: 3x3 conv 256->19 on 256x256, fp32 NCHW out ----------------
__global__ __launch_bounds__(256, 2)
void conv4b_k(const __bf16* __restrict__ y4, const __bf16* __restrict__ wp,
              float* __restrict__ outp) {
  __shared__ __align__(16) __bf16 tile[2][816 * 8];
  const int tid = threadIdx.x;
  const int lane = tid & 63, wv = tid >> 6;
  const int ln = lane & 15, q = lane >> 4;
  const int xblk = blockIdx.x, strip = blockIdx.y, n = blockIdx.z;
  const int oy0 = strip * 4, ox0 = xblk * 32;

  for (int t = tid; t < 1632; t += 256) ((uint4*)tile)[t] = make_uint4(0, 0, 0, 0);

  v4f acc[2][2];
#pragma unroll
  for (int mf = 0; mf < 2; ++mf)
#pragma unroll
    for (int nf = 0; nf < 2; ++nf)
#pragma unroll
      for (int r = 0; r < 4; ++r) acc[mf][nf][r] = 0.f;

  const __bf16* pa[2];
#pragma unroll
  for (int mf = 0; mf < 2; ++mf)
    pa[mf] = wp + (size_t)(mf * 16 + ln) * 256 + q * 8;
  int pixb[2];
#pragma unroll
  for (int nf = 0; nf < 2; ++nf) {
    int n_l = wv * 32 + nf * 16 + ln;
    pixb[nf] = (n_l >> 5) * 34 + (n_l & 31);
  }
  const __bf16* src = y4 + (size_t)n * 65536 * 256;
  const int gx = ox0 - 1 + lane;
  const bool xin = (lane < 34) && (gx >= 0) && (gx < 256);
  __syncthreads();

  // stage chunk 0 -> buf 0
#pragma unroll
  for (int t2 = 0; t2 < 6; ++t2) {
    int y = oy0 - 1 + t2;
    if (y >= 0 && y < 256 && xin)
      g2l16(&tile[0][(wv * 204 + t2 * 34) * 8],
            src + ((size_t)(y * 256 + gx) * 256 + wv * 8));
  }
  __syncthreads();

  for (int kc = 0; kc < 8; ++kc) {
    const int tb = kc & 1;
    if (kc + 1 < 8) {
      const int c1 = (kc + 1) * 32;
#pragma unroll
      for (int t2 = 0; t2 < 6; ++t2) {
        int y = oy0 - 1 + t2;
        if (y >= 0 && y < 256 && xin)
          g2l16(&tile[tb ^ 1][(wv * 204 + t2 * 34) * 8],
                src + ((size_t)(y * 256 + gx) * 256 + c1 + wv * 8));
      }
    }
    const int ci0 = kc * 32;
#pragma unroll
    for (int tap = 0; tap < 9; ++tap) {
      const int ty = tap / 3, tx = tap % 3;
      v8bf bfr[2];
#pragma unroll
      for (int nf = 0; nf < 2; ++nf)
        bfr[nf] = *(const v8bf*)&tile[tb][(q * 204 + pixb[nf] + ty * 34 + tx) * 8];
      const size_t toff = (size_t)tap * 32 * 256 + ci0;
#pragma unroll
      for (int mf = 0; mf < 2; ++mf) {
        v8bf af = *(const v8bf*)(pa[mf] + toff);
#pragma unroll
        for (int nf = 0; nf < 2; ++nf)
          acc[mf][nf] = MFMA16(af, bfr[nf], acc[mf][nf]);
      }
    }
    __syncthreads();
  }

#pragma unroll
  for (int mf = 0; mf < 2; ++mf) {
    const int m_l = mf * 16 + q * 4;
#pragma unroll
    for (int nf = 0; nf < 2; ++nf) {
      const int n_l = wv * 32 + nf * 16 + ln;
      const int oy = oy0 + (n_l >> 5), ox = ox0 + (n_l & 31);
#pragma unroll
      for (int r = 0; r < 4; ++r) {
        int co = m_l + r;
        if (co < 19)
          outp[(((size_t)n * 19 + co) * 256 + oy) * 256 + ox] = acc[mf][nf][r];
      }
    }
  }
}

// ---------------- softmax kernels ----------------

__global__ void softmax1024(const float* __restrict__ S, __bf16* __restrict__ O) {
  __shared__ float red[256];
  const int row = blockIdx.x, tid = threadIdx.x;
  const float* p = S + (size_t)row * 1024;
  float v0 = p[tid], v1 = p[tid + 256], v2 = p[tid + 512], v3 = p[tid + 768];
  float m = fmaxf(fmaxf(v0, v1), fmaxf(v2, v3));
  red[tid] = m; __syncthreads();
  for (int s = 128; s > 0; s >>= 1) { if (tid < s) red[tid] = fmaxf(red[tid], red[tid + s]); __syncthreads(); }
  m = red[0]; __syncthreads();
  v0 = __expf(v0 - m); v1 = __expf(v1 - m); v2 = __expf(v2 - m); v3 = __expf(v3 - m);
  red[tid] = v0 + v1 + v2 + v3; __syncthreads();
  for (int s = 128; s > 0; s >>= 1) { if (tid < s) red[tid] += red[tid + s]; __syncthreads(); }
  float inv = 1.0f / red[0];
  __bf16* o = O + (size_t)row * 1024;
  o[tid] = (__bf16)(v0 * inv); o[tid + 256] = (__bf16)(v1 * inv);
  o[tid + 512] = (__bf16)(v2 * inv); o[tid + 768] = (__bf16)(v3 * inv);
}

// softmax rows of Scc[c][d] (512 wide), writes transposed: O[d*512+c] = Asm[c][d]
__global__ void softmaxT512(const float* __restrict__ S, __bf16* __restrict__ O) {
  __shared__ float red[256];
  const int row = blockIdx.x, tid = threadIdx.x;
  const float* p = S + (size_t)row * 512;
  float v0 = p[tid], v1 = p[tid + 256];
  float m = fmaxf(v0, v1);
  red[tid] = m; __syncthreads();
  for (int s = 128; s > 0; s >>= 1) { if (tid < s) red[tid] = fmaxf(red[tid], red[tid + s]); __syncthreads(); }
  m = red[0]; __syncthreads();
  v0 = __expf(v0 - m); v1 = __expf(v1 - m);
  red[tid] = v0 + v1; __syncthreads();
  for (int s = 128; s > 0; s >>= 1) { if (tid < s) red[tid] += red[tid + s]; __syncthreads(); }
  float inv = 1.0f / red[0];
  int n = row >> 9, c = row & 511;
  __bf16* o = O + (size_t)n * 262144 + c;
  o[(size_t)tid * 512] = (__bf16)(v0 * inv);
  o[(size_t)(tid + 256) * 512] = (__bf16)(v1 * inv);
}

// z = y1 + y2 + gamma*E + beta*X
__global__ void combine_z(const __bf16* __restrict__ y12, const __bf16* __restrict__ E,
                          const __bf16* __restrict__ X, const float* __restrict__ gp,
                          const float* __restrict__ bp, __bf16* __restrict__ z) {
  size_t i = (size_t)blockIdx.x * 256 + threadIdx.x;
  int pg = (int)(i >> 9), c = (int)(i & 511);
  float g = gp[0], b = bp[0];
  float v = (float)y12[(size_t)pg * 1024 + c] + (float)y12[(size_t)pg * 1024 + 512 + c] +
            g * (float)E[i] + b * (float)X[i];
  z[i] = (__bf16)v;
}

// ---------------- launcher ----------------

extern "C" void kernel_launch(void* const* d_in, const int* in_sizes, int n_in,
                              void* d_out, int out_size, void* d_ws, size_t ws_size,
                              hipStream_t stream) {
  const float* x    = (const float*)d_in[0];
  const float* w1   = (const float*)d_in[1];
  const float* bn1g = (const float*)d_in[2];
  const float* bn1b = (const float*)d_in[3];
  const float* bn1m = (const float*)d_in[4];
  const float* bn1v = (const float*)d_in[5];
  const float* w2   = (const float*)d_in[6];
  const float* bn2g = (const float*)d_in[7];
  const float* bn2b = (const float*)d_in[8];
  const float* bn2m = (const float*)d_in[9];
  const float* bn2v = (const float*)d_in[10];
  const float* wB   = (const float*)d_in[11];
  const float* gam  = (const float*)d_in[12];
  const float* bet  = (const float*)d_in[13];
  const float* w3   = (const float*)d_in[14];
  const float* bn3g = (const float*)d_in[15];
  const float* bn3b = (const float*)d_in[16];
  const float* bn3m = (const float*)d_in[17];
  const float* bn3v = (const float*)d_in[18];
  const float* w4a  = (const float*)d_in[19];
  const float* bn4g = (const float*)d_in[20];
  const float* bn4b = (const float*)d_in[21];
  const float* bn4m = (const float*)d_in[22];
  const float* bn4v = (const float*)d_in[23];
  const float* w4b  = (const float*)d_in[24];

  char* ws = (char*)d_ws;
  size_t off = 0;
  auto take = [&](size_t bytes) -> char* {
    char* p = ws + off;
    off += (bytes + 255) & ~(size_t)255;
    return p;
  };
  __bf16* w12b  = (__bf16*)take(9ULL * 1024 * 2048 * 2);
  __bf16* w3b   = (__bf16*)take(9ULL * 512 * 512 * 2);
  __bf16* w4ab  = (__bf16*)take(9ULL * 256 * 512 * 2);
  __bf16* w4bb  = (__bf16*)take(9ULL * 32 * 256 * 2);
  __bf16* wBb   = (__bf16*)take(512ULL * 512 * 2);
  float*  sc12  = (float*)take(1024 * 4);
  float*  bi12  = (float*)take(1024 * 4);
  float*  sc3   = (float*)take(512 * 4);
  float*  bi3   = (float*)take(512 * 4);
  float*  sc4   = (float*)take(256 * 4);
  float*  bi4   = (float*)take(256 * 4);
  __bf16* xb    = (__bf16*)take(4ULL * 1024 * 2048 * 2);
  __bf16* y12   = (__bf16*)take(4ULL * 1024 * 1024 * 2);
  __bf16* Bm_pc = (__bf16*)take(4ULL * 1024 * 512 * 2);
  __bf16* Bm_cp = (__bf16*)take(4ULL * 512 * 1024 * 2);
  float*  Smat  = (float*)take(4ULL * 1024 * 1024 * 4);
  __bf16* Ssm   = (__bf16*)take(4ULL * 1024 * 1024 * 2);
  __bf16* E_pc  = (__bf16*)take(4ULL * 1024 * 512 * 2);
  __bf16* y2t   = (__bf16*)take(4ULL * 512 * 1024 * 2);
  float*  Scc   = (float*)take(4ULL * 512 * 512 * 4);
  __bf16* AsmT  = (__bf16*)take(4ULL * 512 * 512 * 2);
  __bf16* X_pc  = (__bf16*)take(4ULL * 1024 * 512 * 2);
  __bf16* zb    = (__bf16*)take(4ULL * 1024 * 512 * 2);
  __bf16* y4    = (__bf16*)take(4ULL * 65536 * 256 * 2);
  __bf16* y3    = (__bf16*)take(4ULL * 1024 * 512 * 2);

  // prep
  bnprep<<<2, 256, 0, stream>>>(bn1g, bn1b, bn1m, bn1v, sc12, bi12, 512);
  bnprep<<<2, 256, 0, stream>>>(bn2g, bn2b, bn2m, bn2v, sc12 + 512, bi12 + 512, 512);
  bnprep<<<2, 256, 0, stream>>>(bn3g, bn3b, bn3m, bn3v, sc3, bi3, 512);
  bnprep<<<1, 256, 0, stream>>>(bn4g, bn4b, bn4m, bn4v, sc4, bi4, 256);
  pack_w<<<4096, 256, 0, stream>>>(w1, w12b, 512, 512, 0, 1024, 2048, 9);
  pack_w<<<4096, 256, 0, stream>>>(w2, w12b, 512, 512, 512, 1024, 2048, 9);
  pack_w<<<1024, 256, 0, stream>>>(w3, w3b, 512, 512, 0, 512, 512, 9);
  pack_w<<<512, 256, 0, stream>>>(w4a, w4ab, 256, 256, 0, 256, 512, 9);
  pack_w<<<32, 256, 0, stream>>>(w4b, w4bb, 32, 19, 0, 32, 256, 9);
  pack_w<<<1024, 256, 0, stream>>>(wB, wBb, 512, 512, 0, 512, 512, 1);
  cast_x_k<<<dim3(16, 32, 4), 256, 0, stream>>>(x, xb);

  // conv1 + conv2 fused as one GEMM (co 0..511 = conv1, 512..1023 = conv2)
  conv3x3_32<2048, 64><<<dim3(32, 8), 256, 0, stream>>>(xb, w12b, sc12, bi12, y12, 1024);

  // position attention
  gemm_nt<<<dim3(8, 4, 4), 256, 0, stream>>>(wBb, y12, 0, 1048576, 512, 1024, 16, 2,
                                             Bm_pc, Bm_cp, 524288, 512);
  gemm_nt<<<dim3(8, 8, 4), 256, 0, stream>>>(Bm_pc, Bm_pc, 524288, 524288, 512, 512, 16, 1,
                                             Smat, nullptr, 1048576, 1024);
  softmax1024<<<4096, 256, 0, stream>>>(Smat, Ssm);
  gemm_nt<<<dim3(8, 4, 4), 256, 0, stream>>>(Bm_cp, Ssm, 524288, 1048576, 1024, 1024, 32, 0,
                                             E_pc, nullptr, 524288, 512);

  // channel attention
  trans_y2<<<dim3(16, 8, 4), 256, 0, stream>>>(y12, y2t);
  gemm_nt<<<dim3(4, 4, 4), 256, 0, stream>>>(y2t, y2t, 524288, 524288, 1024, 1024, 32, 1,
                                             Scc, nullptr, 262144, 512);
  softmaxT512<<<2048, 256, 0, stream>>>(Scc, AsmT);
  gemm_nt<<<dim3(8, 4, 4), 256, 0, stream>>>(AsmT, y12 + 512, 262144, 1048576, 512, 1024, 16, 0,
                                             X_pc, nullptr, 524288, 512);

  // z = pa + ca
  combine_z<<<8192, 256, 0, stream>>>(y12, E_pc, X_pc, gam, bet, zb);

  // conv3
  conv3x3_32<512, 16><<<dim3(32, 4), 256, 0, stream>>>(zb, w3b, sc3, bi3, y3, 512);

  // conv4a fused with x8 bilinear upsample
  conv4a_up<<<dim3(8, 128, 4), 256, 0, stream>>>(y3, w4ab, sc4, bi4, y4);

  // conv4b -> d_out (fp32 NCHW)
  conv4b_k<<<dim3(8, 64, 4), 256, 0, stream>>>(y4, w4bb, (float*)d_out);
}

// Round 4
// 1307.125 us; speedup vs baseline: 1.7210x; 1.6149x over previous
//
#include <hip/hip_runtime.h>
#include <stdint.h>

typedef __bf16 v8bf __attribute__((ext_vector_type(8)));
typedef float  v4f  __attribute__((ext_vector_type(4)));

#define MFMA16(a,b,c) __builtin_amdgcn_mfma_f32_16x16x32_bf16((a),(b),(c),0,0,0)

__device__ __forceinline__ void g2l16(void* lds, const void* g) {
  __builtin_amdgcn_global_load_lds(
      (__attribute__((address_space(1))) unsigned int*)g,
      (__attribute__((address_space(3))) unsigned int*)lds, 16, 0, 0);
}

// ---------------- small prep kernels ----------------

__global__ void bnprep(const float* __restrict__ g, const float* __restrict__ b,
                       const float* __restrict__ m, const float* __restrict__ v,
                       float* __restrict__ sc, float* __restrict__ bi, int C) {
  int i = blockIdx.x * 256 + threadIdx.x;
  if (i < C) {
    float s = g[i] * rsqrtf(v[i] + 1e-5f);
    sc[i] = s;
    bi[i] = b[i] - m[i] * s;
  }
}

// OIHW fp32 -> [tap][co][ci] bf16 (co may be zero-padded)
__global__ void pack_w(const float* __restrict__ src, __bf16* __restrict__ dst,
                       int co_cnt, int co_src, int co_off, int co_tot, int ci, int taps) {
  int idx = blockIdx.x * 256 + threadIdx.x;
  if (idx >= co_cnt * ci) return;
  int c = idx % ci, co = idx / ci;
  for (int t = 0; t < taps; ++t) {
    float v = (co < co_src) ? src[((size_t)co * ci + c) * taps + t] : 0.f;
    dst[((size_t)t * co_tot + co_off + co) * ci + c] = (__bf16)v;
  }
}

// x NCHW fp32 -> xb [n][p][2048] bf16
__global__ void cast_x_k(const float* __restrict__ x, __bf16* __restrict__ xb) {
  __shared__ float tl[64][65];
  int p0 = blockIdx.x * 64, c0 = blockIdx.y * 64, n = blockIdx.z;
  const float* xin = x + (size_t)n * 2048 * 1024;
  for (int it = 0; it < 16; ++it) {
    int idx = it * 256 + threadIdx.x;
    int px = idx & 63, cl = idx >> 6;
    tl[px][cl] = xin[(size_t)(c0 + cl) * 1024 + p0 + px];
  }
  __syncthreads();
  for (int it = 0; it < 16; ++it) {
    int idx = it * 256 + threadIdx.x;
    int cl = idx & 63, px = idx >> 6;
    xb[((size_t)n * 1024 + p0 + px) * 2048 + c0 + cl] = (__bf16)tl[px][cl];
  }
}

// y12[:,512:1024] ([n][p][1024]) -> y2t [n][c][p] bf16
__global__ void trans_y2(const __bf16* __restrict__ y12, __bf16* __restrict__ y2t) {
  __shared__ __bf16 tl[64][72];
  int p0 = blockIdx.x * 64, c0 = blockIdx.y * 64, n = blockIdx.z;
  for (int it = 0; it < 16; ++it) {
    int idx = it * 256 + threadIdx.x;
    int cl = idx & 63, px = idx >> 6;
    tl[px][cl] = y12[((size_t)n * 1024 + p0 + px) * 1024 + 512 + c0 + cl];
  }
  __syncthreads();
  for (int it = 0; it < 16; ++it) {
    int idx = it * 256 + threadIdx.x;
    int px = idx & 63, cl = idx >> 6;
    y2t[((size_t)n * 512 + c0 + cl) * 1024 + p0 + px] = tl[px][cl];
  }
}

// ---------------- generic 128x128 GEMM, single-barrier double-buffered ----------------
// D[m][n] = sum_k A[m][k]*B[n][k]
// mode 0: bf16 out[P*ldo + m]; mode 1: f32 out[m*ldo + P];
// mode 2: mode0 + bf16 out2[m*1024 + P]; mode 3: f32 out[P*ldo + m]
__global__ __launch_bounds__(256, 2)
void gemm_nt(const __bf16* __restrict__ A, const __bf16* __restrict__ B,
             size_t aB, size_t bB, int lda, int ldb, int kch, int mode,
             void* __restrict__ out, void* __restrict__ out2, size_t oB, int ldo) {
  __shared__ __align__(16) __bf16 tile[2][4 * 128 * 8];
  const int tid = threadIdx.x;
  const int lane = tid & 63, wv = tid >> 6;
  const int ln = lane & 15, q = lane >> 4;
  const int wm = wv >> 1, wn = wv & 1;
  const int p0 = blockIdx.x * 128, mb = blockIdx.y * 128, z = blockIdx.z;
  A += (size_t)z * aB; B += (size_t)z * bB;

  v4f acc[4][4];
#pragma unroll
  for (int mf = 0; mf < 4; ++mf)
#pragma unroll
    for (int nf = 0; nf < 4; ++nf)
#pragma unroll
      for (int r = 0; r < 4; ++r) acc[mf][nf][r] = 0.f;

  const __bf16* pa[4];
#pragma unroll
  for (int mf = 0; mf < 4; ++mf)
    pa[mf] = A + (size_t)(mb + wm * 64 + mf * 16 + ln) * lda + q * 8;

  // stage chunk 0 -> buf 0
#pragma unroll
  for (int t2 = 0; t2 < 2; ++t2)
    g2l16(&tile[0][(wv * 128 + t2 * 64) * 8],
          B + (size_t)(p0 + t2 * 64 + lane) * ldb + wv * 8);
  __syncthreads();

  for (int kc = 0; kc < kch; ++kc) {
    const int tb = kc & 1;
    if (kc + 1 < kch) {
      const int c1 = (kc + 1) * 32;
#pragma unroll
      for (int t2 = 0; t2 < 2; ++t2)
        g2l16(&tile[tb ^ 1][(wv * 128 + t2 * 64) * 8],
              B + (size_t)(p0 + t2 * 64 + lane) * ldb + c1 + wv * 8);
    }
    const int c0 = kc * 32;
    v8bf bfr[4];
#pragma unroll
    for (int nf = 0; nf < 4; ++nf)
      bfr[nf] = *(const v8bf*)&tile[tb][(q * 128 + wn * 64 + nf * 16 + ln) * 8];
#pragma unroll
    for (int mf = 0; mf < 4; ++mf) {
      v8bf af = *(const v8bf*)(pa[mf] + c0);
#pragma unroll
      for (int nf = 0; nf < 4; ++nf)
        acc[mf][nf] = MFMA16(af, bfr[nf], acc[mf][nf]);
    }
    __syncthreads();
  }

#pragma unroll
  for (int mf = 0; mf < 4; ++mf) {
    const int m_l = wm * 64 + mf * 16 + q * 4;
#pragma unroll
    for (int nf = 0; nf < 4; ++nf) {
      const int n_l = wn * 64 + nf * 16 + ln;
      const int P = p0 + n_l;
      if (mode == 1) {
        float* o = (float*)out + (size_t)z * oB;
#pragma unroll
        for (int r = 0; r < 4; ++r)
          o[(size_t)(mb + m_l + r) * ldo + P] = acc[mf][nf][r];
      } else if (mode == 3) {
        float* o = (float*)out + (size_t)z * oB;
        v4f v;
#pragma unroll
        for (int r = 0; r < 4; ++r) v[r] = acc[mf][nf][r];
        *(v4f*)(o + (size_t)P * ldo + mb + m_l) = v;
      } else {
        __bf16* o = (__bf16*)out + (size_t)z * oB;
        union { __bf16 h[4]; uint2 u; } pk;
#pragma unroll
        for (int r = 0; r < 4; ++r) pk.h[r] = (__bf16)acc[mf][nf][r];
        *(uint2*)(o + (size_t)P * ldo + mb + m_l) = pk.u;
        if (mode == 2) {
          __bf16* o2 = (__bf16*)out2 + (size_t)z * oB;
#pragma unroll
          for (int r = 0; r < 4; ++r)
            o2[(size_t)(mb + m_l + r) * 1024 + P] = pk.h[r];
        }
      }
    }
  }
}

// ---------------- 3x3 conv on 32x32 images, single-barrier double-buffered ----------------
// in: [n][1024][CI] bf16 NHWC ; wp: [9][CO][CI] ; out: [n][1024][CO] bf16, bn+relu
template <int CI, int KCH>
__global__ __launch_bounds__(256, 2)
void conv3x3_32(const __bf16* __restrict__ in, const __bf16* __restrict__ wp,
                const float* __restrict__ sc, const float* __restrict__ bi,
                __bf16* __restrict__ out, const int CO) {
  __shared__ __align__(16) __bf16 tile[2][816 * 8];  // [buf][kgrp*204 + pix][8ci]
  __shared__ float s_sc[128], s_bi[128];
  const int tid = threadIdx.x;
  const int lane = tid & 63, wv = tid >> 6;
  const int ln = lane & 15, q = lane >> 4;
  const int pblk = blockIdx.x, cb = blockIdx.y;
  const int n = pblk >> 3, y0 = (pblk & 7) << 2;
  const int wm = wv >> 1, wn = wv & 1;

  if (tid < 128) { int c = cb * 128 + tid; s_sc[tid] = sc[c]; s_bi[tid] = bi[c]; }
  for (int t = tid; t < 1632; t += 256) ((uint4*)tile)[t] = make_uint4(0, 0, 0, 0);

  v4f acc[4][4];
#pragma unroll
  for (int mf = 0; mf < 4; ++mf)
#pragma unroll
    for (int nf = 0; nf < 4; ++nf)
#pragma unroll
      for (int r = 0; r < 4; ++r) acc[mf][nf][r] = 0.f;

  const __bf16* pa[4];
#pragma unroll
  for (int mf = 0; mf < 4; ++mf) {
    int co = cb * 128 + wm * 64 + mf * 16 + ln;
    pa[mf] = wp + (size_t)co * CI + q * 8;
  }
  int pixb[4];
#pragma unroll
  for (int nf = 0; nf < 4; ++nf) {
    int n_l = wn * 64 + nf * 16 + ln;
    pixb[nf] = (n_l >> 5) * 34 + (n_l & 31);
  }
  const __bf16* inb = in + (size_t)n * 1024 * CI;
  __syncthreads();  // zero-init visible before first g2l lands

  // stage chunk 0 -> buf 0
  if (lane < 32) {
#pragma unroll
    for (int t2 = 0; t2 < 6; ++t2) {
      int y = y0 - 1 + t2;
      if (y >= 0 && y < 32)
        g2l16(&tile[0][(wv * 204 + t2 * 34 + 1) * 8],
              inb + ((size_t)(y * 32 + lane) * CI + wv * 8));
    }
  }
  __syncthreads();

  for (int kc = 0; kc < KCH; ++kc) {
    const int tb = kc & 1;
    if (kc + 1 < KCH && lane < 32) {
      const int c1 = (kc + 1) * 32;
#pragma unroll
      for (int t2 = 0; t2 < 6; ++t2) {
        int y = y0 - 1 + t2;
        if (y >= 0 && y < 32)
          g2l16(&tile[tb ^ 1][(wv * 204 + t2 * 34 + 1) * 8],
                inb + ((size_t)(y * 32 + lane) * CI + c1 + wv * 8));
      }
    }
    const int ci0 = kc * 32;
#pragma unroll
    for (int tap = 0; tap < 9; ++tap) {
      const int ty = tap / 3, tx = tap % 3;
      v8bf bfr[4];
#pragma unroll
      for (int nf = 0; nf < 4; ++nf)
        bfr[nf] = *(const v8bf*)&tile[tb][(q * 204 + pixb[nf] + ty * 34 + tx) * 8];
      const size_t toff = (size_t)tap * CO * CI + ci0;
#pragma unroll
      for (int mf = 0; mf < 4; ++mf) {
        v8bf af = *(const v8bf*)(pa[mf] + toff);
#pragma unroll
        for (int nf = 0; nf < 4; ++nf)
          acc[mf][nf] = MFMA16(af, bfr[nf], acc[mf][nf]);
      }
    }
    __syncthreads();
  }

#pragma unroll
  for (int mf = 0; mf < 4; ++mf) {
    const int m_l = wm * 64 + mf * 16 + q * 4;
#pragma unroll
    for (int nf = 0; nf < 4; ++nf) {
      const int n_l = wn * 64 + nf * 16 + ln;
      const int p_img = (y0 + (n_l >> 5)) * 32 + (n_l & 31);
      union { __bf16 h[4]; uint2 u; } pk;
#pragma unroll
      for (int r = 0; r < 4; ++r) {
        float v = acc[mf][nf][r] * s_sc[m_l + r] + s_bi[m_l + r];
        pk.h[r] = (__bf16)fmaxf(v, 0.f);
      }
      *(uint2*)(out + (size_t)(n * 1024 + p_img) * CO + cb * 128 + m_l) = pk.u;
    }
  }
}

// ---------------- up_combine: y4[f,co] = relu(bn4( sum_{tap,2x2} w_bilin * D )) ----------------
// D: [n][1024 coarse px][9*256] fp32 ; y4: [n][65536][256] bf16
// thread = (xrun of 16 fine cols) x (4 co); consecutive fine cols reuse coarse cells in regs.
__global__ __launch_bounds__(256, 4)
void up_combine(const float* __restrict__ D, const float* __restrict__ sc,
                const float* __restrict__ bi, __bf16* __restrict__ y4) {
  const int tid = threadIdx.x;
  const int coq = blockIdx.x;   // 0..3 (64-co quarter)
  const int oy = blockIdx.y;    // fine row 0..255
  const int n = blockIdx.z;
  const int co = coq * 64 + (tid & 15) * 4;
  const int px0 = (tid >> 4) * 16;

  const v4f s4 = *(const v4f*)(sc + co);
  const v4f b4 = *(const v4f*)(bi + co);

  v4f acc[16];
#pragma unroll
  for (int j = 0; j < 16; ++j)
#pragma unroll
    for (int r = 0; r < 4; ++r) acc[j][r] = 0.f;

  const float* Dn = D + (size_t)n * 1024 * 2304;

#pragma unroll
  for (int ty = 0; ty < 3; ++ty) {
    int fy = oy + ty - 1;
    if (fy < 0 || fy > 255) continue;
    float syf = fy * (31.0f / 255.0f);
    int rA = (int)syf; float wy = syf - rA;
    int rB = rA < 31 ? rA + 1 : 31;
    float wA = 1.f - wy, wB = wy;
    const float* rowA = Dn + (size_t)rA * 32 * 2304;
    const float* rowB = Dn + (size_t)rB * 32 * 2304;
#pragma unroll
    for (int tx = 0; tx < 3; ++tx) {
      const int tco = (ty * 3 + tx) * 256 + co;
      int cur = -99;
      v4f a0{}, a1{}, b0{}, b1{};
#pragma unroll
      for (int j = 0; j < 16; ++j) {
        int fx = px0 + j + tx - 1;
        if (fx < 0 || fx > 255) continue;
        float sxf = fx * (31.0f / 255.0f);
        int c0 = (int)sxf; float wx = sxf - c0;
        if (c0 != cur) {
          cur = c0;
          int c1 = c0 < 31 ? c0 + 1 : 31;
          a0 = *(const v4f*)(rowA + (size_t)c0 * 2304 + tco);
          a1 = *(const v4f*)(rowA + (size_t)c1 * 2304 + tco);
          b0 = *(const v4f*)(rowB + (size_t)c0 * 2304 + tco);
          b1 = *(const v4f*)(rowB + (size_t)c1 * 2304 + tco);
        }
        float wxA = 1.f - wx;
        float cA = wA * wxA, cB = wA * wx, cC = wB * wxA, cD = wB * wx;
#pragma unroll
        for (int r = 0; r < 4; ++r)
          acc[j][r] += cA * a0[r] + cB * a1[r] + cC * b0[r] + cD * b1[r];
      }
    }
  }

  __bf16* ob = y4 + (((size_t)n * 65536 + (size_t)oy * 256 + px0) * 256 + co);
#pragma unroll
  for (int j = 0; j < 16; ++j) {
    union { __bf16 h[4]; uint2 u; } pk;
#pragma unroll
    for (int r = 0; r < 4; ++r) {
      float v = acc[j][r] * s4[r] + b4[r];
      pk.h[r] = (__bf16)fmaxf(v, 0.f);
    }
    *(uint2*)(ob + (size_t)j * 256) = pk.u;
  }
}

// ---------------- conv4b: 3x3 conv 256->19 on 256x256, fp32 NCHW out ----------------
__global__ __launch_bounds__(256, 2)
void conv4b_k(const __bf16* __restrict__ y4, const __bf16* __restrict__ wp,
              float* __restrict__ outp) {
  __shared__ __align__(16) __bf16 tile[2][816 * 8];
  const int tid = threadIdx.x;
  const int lane = tid & 63, wv = tid >> 6;
  const int ln = lane & 15, q = lane >> 4;
  const int xblk = blockIdx.x, strip = blockIdx.y, n = blockIdx.z;
  const int oy0 = strip * 4, ox0 = xblk * 32;

  for (int t = tid; t < 1632; t += 256) ((uint4*)tile)[t] = make_uint4(0, 0, 0, 0);

  v4f acc[2][2];
#pragma unroll
  for (int mf = 0; mf < 2; ++mf)
#pragma unroll
    for (int nf = 0; nf < 2; ++nf)
#pragma unroll
      for (int r = 0; r < 4; ++r) acc[mf][nf][r] = 0.f;

  const __bf16* pa[2];
#pragma unroll
  for (int mf = 0; mf < 2; ++mf)
    pa[mf] = wp + (size_t)(mf * 16 + ln) * 256 + q * 8;
  int pixb[2];
#pragma unroll
  for (int nf = 0; nf < 2; ++nf) {
    int n_l = wv * 32 + nf * 16 + ln;
    pixb[nf] = (n_l >> 5) * 34 + (n_l & 31);
  }
  const __bf16* src = y4 + (size_t)n * 65536 * 256;
  const int gx = ox0 - 1 + lane;
  const bool xin = (lane < 34) && (gx >= 0) && (gx < 256);
  __syncthreads();

  // stage chunk 0 -> buf 0
#pragma unroll
  for (int t2 = 0; t2 < 6; ++t2) {
    int y = oy0 - 1 + t2;
    if (y >= 0 && y < 256 && xin)
      g2l16(&tile[0][(wv * 204 + t2 * 34) * 8],
            src + ((size_t)(y * 256 + gx) * 256 + wv * 8));
  }
  __syncthreads();

  for (int kc = 0; kc < 8; ++kc) {
    const int tb = kc & 1;
    if (kc + 1 < 8) {
      const int c1 = (kc + 1) * 32;
#pragma unroll
      for (int t2 = 0; t2 < 6; ++t2) {
        int y = oy0 - 1 + t2;
        if (y >= 0 && y < 256 && xin)
          g2l16(&tile[tb ^ 1][(wv * 204 + t2 * 34) * 8],
                src + ((size_t)(y * 256 + gx) * 256 + c1 + wv * 8));
      }
    }
    const int ci0 = kc * 32;
#pragma unroll
    for (int tap = 0; tap < 9; ++tap) {
      const int ty = tap / 3, tx = tap % 3;
      v8bf bfr[2];
#pragma unroll
      for (int nf = 0; nf < 2; ++nf)
        bfr[nf] = *(const v8bf*)&tile[tb][(q * 204 + pixb[nf] + ty * 34 + tx) * 8];
      const size_t toff = (size_t)tap * 32 * 256 + ci0;
#pragma unroll
      for (int mf = 0; mf < 2; ++mf) {
        v8bf af = *(const v8bf*)(pa[mf] + toff);
#pragma unroll
        for (int nf = 0; nf < 2; ++nf)
          acc[mf][nf] = MFMA16(af, bfr[nf], acc[mf][nf]);
      }
    }
    __syncthreads();
  }

#pragma unroll
  for (int mf = 0; mf < 2; ++mf) {
    const int m_l = mf * 16 + q * 4;
#pragma unroll
    for (int nf = 0; nf < 2; ++nf) {
      const int n_l = wv * 32 + nf * 16 + ln;
      const int oy = oy0 + (n_l >> 5), ox = ox0 + (n_l & 31);
#pragma unroll
      for (int r = 0; r < 4; ++r) {
        int co = m_l + r;
        if (co < 19)
          outp[(((size_t)n * 19 + co) * 256 + oy) * 256 + ox] = acc[mf][nf][r];
      }
    }
  }
}

// ---------------- softmax kernels ----------------

__global__ void softmax1024(const float* __restrict__ S, __bf16* __restrict__ O) {
  __shared__ float red[256];
  const int row = blockIdx.x, tid = threadIdx.x;
  const float* p = S + (size_t)row * 1024;
  float v0 = p[tid], v1 = p[tid + 256], v2 = p[tid + 512], v3 = p[tid + 768];
  float m = fmaxf(fmaxf(v0, v1), fmaxf(v2, v3));
  red[tid] = m; __syncthreads();
  for (int s = 128; s > 0; s >>= 1) { if (tid < s) red[tid] = fmaxf(red[tid], red[tid + s]); __syncthreads(); }
  m = red[0]; __syncthreads();
  v0 = __expf(v0 - m); v1 = __expf(v1 - m); v2 = __expf(v2 - m); v3 = __expf(v3 - m);
  red[tid] = v0 + v1 + v2 + v3; __syncthreads();
  for (int s = 128; s > 0; s >>= 1) { if (tid < s) red[tid] += red[tid + s]; __syncthreads(); }
  float inv = 1.0f / red[0];
  __bf16* o = O + (size_t)row * 1024;
  o[tid] = (__bf16)(v0 * inv); o[tid + 256] = (__bf16)(v1 * inv);
  o[tid + 512] = (__bf16)(v2 * inv); o[tid + 768] = (__bf16)(v3 * inv);
}

// softmax rows of Scc[c][d] (512 wide), writes transposed: O[d*512+c] = Asm[c][d]
__global__ void softmaxT512(const float* __restrict__ S, __bf16* __restrict__ O) {
  __shared__ float red[256];
  const int row = blockIdx.x, tid = threadIdx.x;
  const float* p = S + (size_t)row * 512;
  float v0 = p[tid], v1 = p[tid + 256];
  float m = fmaxf(v0, v1);
  red[tid] = m; __syncthreads();
  for (int s = 128; s > 0; s >>= 1) { if (tid < s) red[tid] = fmaxf(red[tid], red[tid + s]); __syncthreads(); }
  m = red[0]; __syncthreads();
  v0 = __expf(v0 - m); v1 = __expf(v1 - m);
  red[tid] = v0 + v1; __syncthreads();
  for (int s = 128; s > 0; s >>= 1) { if (tid < s) red[tid] += red[tid + s]; __syncthreads(); }
  float inv = 1.0f / red[0];
  int n = row >> 9, c = row & 511;
  __bf16* o = O + (size_t)n * 262144 + c;
  o[(size_t)tid * 512] = (__bf16)(v0 * inv);
  o[(size_t)(tid + 256) * 512] = (__bf16)(v1 * inv);
}

// z = y1 + y2 + gamma*E + beta*X
__global__ void combine_z(const __bf16* __restrict__ y12, const __bf16* __restrict__ E,
                          const __bf16* __restrict__ X, const float* __restrict__ gp,
                          const float* __restrict__ bp, __bf16* __restrict__ z) {
  size_t i = (size_t)blockIdx.x * 256 + threadIdx.x;
  int pg = (int)(i >> 9), c = (int)(i & 511);
  float g = gp[0], b = bp[0];
  float v = (float)y12[(size_t)pg * 1024 + c] + (float)y12[(size_t)pg * 1024 + 512 + c] +
            g * (float)E[i] + b * (float)X[i];
  z[i] = (__bf16)v;
}

// ---------------- launcher ----------------

extern "C" void kernel_launch(void* const* d_in, const int* in_sizes, int n_in,
                              void* d_out, int out_size, void* d_ws, size_t ws_size,
                              hipStream_t stream) {
  const float* x    = (const float*)d_in[0];
  const float* w1   = (const float*)d_in[1];
  const float* bn1g = (const float*)d_in[2];
  const float* bn1b = (const float*)d_in[3];
  const float* bn1m = (const float*)d_in[4];
  const float* bn1v = (const float*)d_in[5];
  const float* w2   = (const float*)d_in[6];
  const float* bn2g = (const float*)d_in[7];
  const float* bn2b = (const float*)d_in[8];
  const float* bn2m = (const float*)d_in[9];
  const float* bn2v = (const float*)d_in[10];
  const float* wB   = (const float*)d_in[11];
  const float* gam  = (const float*)d_in[12];
  const float* bet  = (const float*)d_in[13];
  const float* w3   = (const float*)d_in[14];
  const float* bn3g = (const float*)d_in[15];
  const float* bn3b = (const float*)d_in[16];
  const float* bn3m = (const float*)d_in[17];
  const float* bn3v = (const float*)d_in[18];
  const float* w4a  = (const float*)d_in[19];
  const float* bn4g = (const float*)d_in[20];
  const float* bn4b = (const float*)d_in[21];
  const float* bn4m = (const float*)d_in[22];
  const float* bn4v = (const float*)d_in[23];
  const float* w4b  = (const float*)d_in[24];

  char* ws = (char*)d_ws;
  size_t off = 0;
  auto take = [&](size_t bytes) -> char* {
    char* p = ws + off;
    off += (bytes + 255) & ~(size_t)255;
    return p;
  };
  __bf16* w12b  = (__bf16*)take(9ULL * 1024 * 2048 * 2);
  __bf16* w3b   = (__bf16*)take(9ULL * 512 * 512 * 2);
  __bf16* w4ab  = (__bf16*)take(9ULL * 256 * 512 * 2);
  __bf16* w4bb  = (__bf16*)take(9ULL * 32 * 256 * 2);
  __bf16* wBb   = (__bf16*)take(512ULL * 512 * 2);
  float*  sc12  = (float*)take(1024 * 4);
  float*  bi12  = (float*)take(1024 * 4);
  float*  sc3   = (float*)take(512 * 4);
  float*  bi3   = (float*)take(512 * 4);
  float*  sc4   = (float*)take(256 * 4);
  float*  bi4   = (float*)take(256 * 4);
  __bf16* xb    = (__bf16*)take(4ULL * 1024 * 2048 * 2);
  __bf16* y12   = (__bf16*)take(4ULL * 1024 * 1024 * 2);
  __bf16* Bm_pc = (__bf16*)take(4ULL * 1024 * 512 * 2);
  __bf16* Bm_cp = (__bf16*)take(4ULL * 512 * 1024 * 2);
  float*  Smat  = (float*)take(4ULL * 1024 * 1024 * 4);
  __bf16* Ssm   = (__bf16*)take(4ULL * 1024 * 1024 * 2);
  __bf16* E_pc  = (__bf16*)take(4ULL * 1024 * 512 * 2);
  __bf16* y2t   = (__bf16*)take(4ULL * 512 * 1024 * 2);
  float*  Scc   = (float*)take(4ULL * 512 * 512 * 4);
  __bf16* AsmT  = (__bf16*)take(4ULL * 512 * 512 * 2);
  __bf16* X_pc  = (__bf16*)take(4ULL * 1024 * 512 * 2);
  __bf16* zb    = (__bf16*)take(4ULL * 1024 * 512 * 2);
  __bf16* y4    = (__bf16*)take(4ULL * 65536 * 256 * 2);
  __bf16* y3    = (__bf16*)take(4ULL * 1024 * 512 * 2);
  // D (coarse tap-GEMM output, 4*1024*2304 fp32 = 37.75 MB) aliases the
  // xb..Smat region (xb+y12+Bm_pc+Bm_cp = 33.6 MB + 4.2 MB of Smat), all of
  // which are dead by the time conv3 has produced y3.
  float* Dmat = (float*)xb;

  // prep
  bnprep<<<2, 256, 0, stream>>>(bn1g, bn1b, bn1m, bn1v, sc12, bi12, 512);
  bnprep<<<2, 256, 0, stream>>>(bn2g, bn2b, bn2m, bn2v, sc12 + 512, bi12 + 512, 512);
  bnprep<<<2, 256, 0, stream>>>(bn3g, bn3b, bn3m, bn3v, sc3, bi3, 512);
  bnprep<<<1, 256, 0, stream>>>(bn4g, bn4b, bn4m, bn4v, sc4, bi4, 256);
  pack_w<<<4096, 256, 0, stream>>>(w1, w12b, 512, 512, 0, 1024, 2048, 9);
  pack_w<<<4096, 256, 0, stream>>>(w2, w12b, 512, 512, 512, 1024, 2048, 9);
  pack_w<<<1024, 256, 0, stream>>>(w3, w3b, 512, 512, 0, 512, 512, 9);
  pack_w<<<512, 256, 0, stream>>>(w4a, w4ab, 256, 256, 0, 256, 512, 9);
  pack_w<<<32, 256, 0, stream>>>(w4b, w4bb, 32, 19, 0, 32, 256, 9);
  pack_w<<<1024, 256, 0, stream>>>(wB, wBb, 512, 512, 0, 512, 512, 1);
  cast_x_k<<<dim3(16, 32, 4), 256, 0, stream>>>(x, xb);

  // conv1 + conv2 fused as one GEMM (co 0..511 = conv1, 512..1023 = conv2)
  conv3x3_32<2048, 64><<<dim3(32, 8), 256, 0, stream>>>(xb, w12b, sc12, bi12, y12, 1024);

  // position attention
  gemm_nt<<<dim3(8, 4, 4), 256, 0, stream>>>(wBb, y12, 0, 1048576, 512, 1024, 16, 2,
                                             Bm_pc, Bm_cp, 524288, 512);
  gemm_nt<<<dim3(8, 8, 4), 256, 0, stream>>>(Bm_pc, Bm_pc, 524288, 524288, 512, 512, 16, 1,
                                             Smat, nullptr, 1048576, 1024);
  softmax1024<<<4096, 256, 0, stream>>>(Smat, Ssm);
  gemm_nt<<<dim3(8, 4, 4), 256, 0, stream>>>(Bm_cp, Ssm, 524288, 1048576, 1024, 1024, 32, 0,
                                             E_pc, nullptr, 524288, 512);

  // channel attention
  trans_y2<<<dim3(16, 8, 4), 256, 0, stream>>>(y12, y2t);
  gemm_nt<<<dim3(4, 4, 4), 256, 0, stream>>>(y2t, y2t, 524288, 524288, 1024, 1024, 32, 1,
                                             Scc, nullptr, 262144, 512);
  softmaxT512<<<2048, 256, 0, stream>>>(Scc, AsmT);
  gemm_nt<<<dim3(8, 4, 4), 256, 0, stream>>>(AsmT, y12 + 512, 262144, 1048576, 512, 1024, 16, 0,
                                             X_pc, nullptr, 524288, 512);

  // z = pa + ca
  combine_z<<<8192, 256, 0, stream>>>(y12, E_pc, X_pc, gam, bet, zb);

  // conv3
  conv3x3_32<512, 16><<<dim3(32, 4), 256, 0, stream>>>(zb, w3b, sc3, bi3, y3, 512);

  // conv4a factored through the linear upsample:
  //   D[n][coarse px][t*256+co] = sum_ci w4a[t,co,ci] * y3[n,px,ci]   (fp32)
  gemm_nt<<<dim3(8, 18, 4), 256, 0, stream>>>(w4ab, y3, 0, 524288, 512, 512, 16, 3,
                                              Dmat, nullptr, 2359296, 2304);
  //   y4[f,co] = relu(bn4( sum_{tap,2x2} w_bilin(f,tap) * D ))
  up_combine<<<dim3(4, 256, 4), 256, 0, stream>>>(Dmat, sc4, bi4, y4);

  // conv4b -> d_out (fp32 NCHW)
  conv4b_k<<<dim3(8, 64, 4), 256, 0, stream>>>(y4, w4bb, (float*)d_out);
}

// Round 5
// 1300.716 us; speedup vs baseline: 1.7295x; 1.0049x over previous
//
#include <hip/hip_runtime.h>
#include <stdint.h>

typedef __bf16 v8bf __attribute__((ext_vector_type(8)));
typedef float  v4f  __attribute__((ext_vector_type(4)));

#define MFMA16(a,b,c) __builtin_amdgcn_mfma_f32_16x16x32_bf16((a),(b),(c),0,0,0)

__device__ __forceinline__ void g2l16(void* lds, const void* g) {
  __builtin_amdgcn_global_load_lds(
      (__attribute__((address_space(1))) unsigned int*)g,
      (__attribute__((address_space(3))) unsigned int*)lds, 16, 0, 0);
}

// ---------------- small prep kernels ----------------

__global__ void bnprep(const float* __restrict__ g, const float* __restrict__ b,
                       const float* __restrict__ m, const float* __restrict__ v,
                       float* __restrict__ sc, float* __restrict__ bi, int C) {
  int i = blockIdx.x * 256 + threadIdx.x;
  if (i < C) {
    float s = g[i] * rsqrtf(v[i] + 1e-5f);
    sc[i] = s;
    bi[i] = b[i] - m[i] * s;
  }
}

// OIHW fp32 -> [tap][co][ci] bf16 (co may be zero-padded)
__global__ void pack_w(const float* __restrict__ src, __bf16* __restrict__ dst,
                       int co_cnt, int co_src, int co_off, int co_tot, int ci, int taps) {
  int idx = blockIdx.x * 256 + threadIdx.x;
  if (idx >= co_cnt * ci) return;
  int c = idx % ci, co = idx / ci;
  for (int t = 0; t < taps; ++t) {
    float v = (co < co_src) ? src[((size_t)co * ci + c) * taps + t] : 0.f;
    dst[((size_t)t * co_tot + co_off + co) * ci + c] = (__bf16)v;
  }
}

// x NCHW fp32 -> xb [n][p][2048] bf16
__global__ void cast_x_k(const float* __restrict__ x, __bf16* __restrict__ xb) {
  __shared__ float tl[64][65];
  int p0 = blockIdx.x * 64, c0 = blockIdx.y * 64, n = blockIdx.z;
  const float* xin = x + (size_t)n * 2048 * 1024;
  for (int it = 0; it < 16; ++it) {
    int idx = it * 256 + threadIdx.x;
    int px = idx & 63, cl = idx >> 6;
    tl[px][cl] = xin[(size_t)(c0 + cl) * 1024 + p0 + px];
  }
  __syncthreads();
  for (int it = 0; it < 16; ++it) {
    int idx = it * 256 + threadIdx.x;
    int cl = idx & 63, px = idx >> 6;
    xb[((size_t)n * 1024 + p0 + px) * 2048 + c0 + cl] = (__bf16)tl[px][cl];
  }
}

// y12[:,512:1024] ([n][p][1024]) -> y2t [n][c][p] bf16
__global__ void trans_y2(const __bf16* __restrict__ y12, __bf16* __restrict__ y2t) {
  __shared__ __bf16 tl[64][72];
  int p0 = blockIdx.x * 64, c0 = blockIdx.y * 64, n = blockIdx.z;
  for (int it = 0; it < 16; ++it) {
    int idx = it * 256 + threadIdx.x;
    int cl = idx & 63, px = idx >> 6;
    tl[px][cl] = y12[((size_t)n * 1024 + p0 + px) * 1024 + 512 + c0 + cl];
  }
  __syncthreads();
  for (int it = 0; it < 16; ++it) {
    int idx = it * 256 + threadIdx.x;
    int px = idx & 63, cl = idx >> 6;
    y2t[((size_t)n * 512 + c0 + cl) * 1024 + p0 + px] = tl[px][cl];
  }
}

// ---------------- generic 128x128 GEMM, single-barrier double-buffered ----------------
// D[m][n] = sum_k A[m][k]*B[n][k]
// mode 0: bf16 out[P*ldo + m]; mode 1: f32 out[m*ldo + P];
// mode 2: mode0 + bf16 out2[m*1024 + P]; mode 3: f32 out[P*ldo + m]
__global__ __launch_bounds__(256, 2)
void gemm_nt(const __bf16* __restrict__ A, const __bf16* __restrict__ B,
             size_t aB, size_t bB, int lda, int ldb, int kch, int mode,
             void* __restrict__ out, void* __restrict__ out2, size_t oB, int ldo) {
  __shared__ __align__(16) __bf16 tile[2][4 * 128 * 8];
  const int tid = threadIdx.x;
  const int lane = tid & 63, wv = tid >> 6;
  const int ln = lane & 15, q = lane >> 4;
  const int wm = wv >> 1, wn = wv & 1;
  const int p0 = blockIdx.x * 128, mb = blockIdx.y * 128, z = blockIdx.z;
  A += (size_t)z * aB; B += (size_t)z * bB;

  v4f acc[4][4];
#pragma unroll
  for (int mf = 0; mf < 4; ++mf)
#pragma unroll
    for (int nf = 0; nf < 4; ++nf)
#pragma unroll
      for (int r = 0; r < 4; ++r) acc[mf][nf][r] = 0.f;

  const __bf16* pa[4];
#pragma unroll
  for (int mf = 0; mf < 4; ++mf)
    pa[mf] = A + (size_t)(mb + wm * 64 + mf * 16 + ln) * lda + q * 8;

  // stage chunk 0 -> buf 0
#pragma unroll
  for (int t2 = 0; t2 < 2; ++t2)
    g2l16(&tile[0][(wv * 128 + t2 * 64) * 8],
          B + (size_t)(p0 + t2 * 64 + lane) * ldb + wv * 8);
  __syncthreads();

  for (int kc = 0; kc < kch; ++kc) {
    const int tb = kc & 1;
    if (kc + 1 < kch) {
      const int c1 = (kc + 1) * 32;
#pragma unroll
      for (int t2 = 0; t2 < 2; ++t2)
        g2l16(&tile[tb ^ 1][(wv * 128 + t2 * 64) * 8],
              B + (size_t)(p0 + t2 * 64 + lane) * ldb + c1 + wv * 8);
    }
    const int c0 = kc * 32;
    v8bf bfr[4];
#pragma unroll
    for (int nf = 0; nf < 4; ++nf)
      bfr[nf] = *(const v8bf*)&tile[tb][(q * 128 + wn * 64 + nf * 16 + ln) * 8];
#pragma unroll
    for (int mf = 0; mf < 4; ++mf) {
      v8bf af = *(const v8bf*)(pa[mf] + c0);
#pragma unroll
      for (int nf = 0; nf < 4; ++nf)
        acc[mf][nf] = MFMA16(af, bfr[nf], acc[mf][nf]);
    }
    __syncthreads();
  }

#pragma unroll
  for (int mf = 0; mf < 4; ++mf) {
    const int m_l = wm * 64 + mf * 16 + q * 4;
#pragma unroll
    for (int nf = 0; nf < 4; ++nf) {
      const int n_l = wn * 64 + nf * 16 + ln;
      const int P = p0 + n_l;
      if (mode == 1) {
        float* o = (float*)out + (size_t)z * oB;
#pragma unroll
        for (int r = 0; r < 4; ++r)
          o[(size_t)(mb + m_l + r) * ldo + P] = acc[mf][nf][r];
      } else if (mode == 3) {
        float* o = (float*)out + (size_t)z * oB;
        v4f v;
#pragma unroll
        for (int r = 0; r < 4; ++r) v[r] = acc[mf][nf][r];
        *(v4f*)(o + (size_t)P * ldo + mb + m_l) = v;
      } else {
        __bf16* o = (__bf16*)out + (size_t)z * oB;
        union { __bf16 h[4]; uint2 u; } pk;
#pragma unroll
        for (int r = 0; r < 4; ++r) pk.h[r] = (__bf16)acc[mf][nf][r];
        *(uint2*)(o + (size_t)P * ldo + mb + m_l) = pk.u;
        if (mode == 2) {
          __bf16* o2 = (__bf16*)out2 + (size_t)z * oB;
#pragma unroll
          for (int r = 0; r < 4; ++r)
            o2[(size_t)(mb + m_l + r) * 1024 + P] = pk.h[r];
        }
      }
    }
  }
}

// ---------------- 3x3 conv on 32x32 images, SPLIT-K, fp32 partials ----------------
// in: [n][1024][CI] bf16 NHWC ; wp: [9][CO][CI]
// part: [KS][n][1024][CO] fp32 (no bn/relu here)
// grid: (32 = n*8strips, CO/128, KS); each z-block does KCH/KS ci-chunks.
template <int CI, int KCH, int KS>
__global__ __launch_bounds__(256, 4)
void conv3x3_sk(const __bf16* __restrict__ in, const __bf16* __restrict__ wp,
                float* __restrict__ part, const int CO) {
  __shared__ __align__(16) __bf16 tile[2][816 * 8];  // [buf][kgrp*204 + pix][8ci]
  const int tid = threadIdx.x;
  const int lane = tid & 63, wv = tid >> 6;
  const int ln = lane & 15, q = lane >> 4;
  const int pblk = blockIdx.x, cb = blockIdx.y, ks = blockIdx.z;
  const int n = pblk >> 3, y0 = (pblk & 7) << 2;
  const int wm = wv >> 1, wn = wv & 1;
  const int KCN = KCH / KS;
  const int kbase = ks * KCN;

  for (int t = tid; t < 1632; t += 256) ((uint4*)tile)[t] = make_uint4(0, 0, 0, 0);

  v4f acc[4][4];
#pragma unroll
  for (int mf = 0; mf < 4; ++mf)
#pragma unroll
    for (int nf = 0; nf < 4; ++nf)
#pragma unroll
      for (int r = 0; r < 4; ++r) acc[mf][nf][r] = 0.f;

  const __bf16* pa[4];
#pragma unroll
  for (int mf = 0; mf < 4; ++mf) {
    int co = cb * 128 + wm * 64 + mf * 16 + ln;
    pa[mf] = wp + (size_t)co * CI + kbase * 32 + q * 8;
  }
  int pixb[4];
#pragma unroll
  for (int nf = 0; nf < 4; ++nf) {
    int n_l = wn * 64 + nf * 16 + ln;
    pixb[nf] = (n_l >> 5) * 34 + (n_l & 31);
  }
  const __bf16* inb = in + (size_t)n * 1024 * CI + kbase * 32;
  __syncthreads();  // zero-init visible before first g2l lands

  // stage chunk 0 -> buf 0
  if (lane < 32) {
#pragma unroll
    for (int t2 = 0; t2 < 6; ++t2) {
      int y = y0 - 1 + t2;
      if (y >= 0 && y < 32)
        g2l16(&tile[0][(wv * 204 + t2 * 34 + 1) * 8],
              inb + ((size_t)(y * 32 + lane) * CI + wv * 8));
    }
  }
  __syncthreads();

  for (int kc = 0; kc < KCN; ++kc) {
    const int tb = kc & 1;
    if (kc + 1 < KCN && lane < 32) {
      const int c1 = (kc + 1) * 32;
#pragma unroll
      for (int t2 = 0; t2 < 6; ++t2) {
        int y = y0 - 1 + t2;
        if (y >= 0 && y < 32)
          g2l16(&tile[tb ^ 1][(wv * 204 + t2 * 34 + 1) * 8],
                inb + ((size_t)(y * 32 + lane) * CI + c1 + wv * 8));
      }
    }
    const int ci0 = kc * 32;
#pragma unroll
    for (int tap = 0; tap < 9; ++tap) {
      const int ty = tap / 3, tx = tap % 3;
      v8bf bfr[4];
#pragma unroll
      for (int nf = 0; nf < 4; ++nf)
        bfr[nf] = *(const v8bf*)&tile[tb][(q * 204 + pixb[nf] + ty * 34 + tx) * 8];
      const size_t toff = (size_t)tap * CO * CI + ci0;
#pragma unroll
      for (int mf = 0; mf < 4; ++mf) {
        v8bf af = *(const v8bf*)(pa[mf] + toff);
#pragma unroll
        for (int nf = 0; nf < 4; ++nf)
          acc[mf][nf] = MFMA16(af, bfr[nf], acc[mf][nf]);
      }
    }
    __syncthreads();
  }

  float* po = part + ((size_t)ks * 4096 + (size_t)n * 1024) * CO;
#pragma unroll
  for (int mf = 0; mf < 4; ++mf) {
    const int m_l = wm * 64 + mf * 16 + q * 4;
#pragma unroll
    for (int nf = 0; nf < 4; ++nf) {
      const int n_l = wn * 64 + nf * 16 + ln;
      const int p_img = (y0 + (n_l >> 5)) * 32 + (n_l & 31);
      *(v4f*)(po + (size_t)p_img * CO + cb * 128 + m_l) = acc[mf][nf];
    }
  }
}

// sum KS fp32 partials, bn+relu, write bf16 [row][CO]
template <int CO, int KS>
__global__ __launch_bounds__(256, 8)
void reduce_bn_relu(const float* __restrict__ part, const float* __restrict__ sc,
                    const float* __restrict__ bi, __bf16* __restrict__ out) {
  const size_t splitStride = (size_t)4096 * CO;
  size_t gi = (size_t)blockIdx.x * 256 + threadIdx.x;  // group of 4 floats
  size_t row = gi / (CO / 4);
  int c4 = (int)(gi % (CO / 4)) * 4;
  const float* p = part + row * CO + c4;
  v4f a = *(const v4f*)p;
#pragma unroll
  for (int s = 1; s < KS; ++s) {
    v4f b = *(const v4f*)(p + s * splitStride);
#pragma unroll
    for (int r = 0; r < 4; ++r) a[r] += b[r];
  }
  const v4f s4 = *(const v4f*)(sc + c4);
  const v4f b4 = *(const v4f*)(bi + c4);
  union { __bf16 h[4]; uint2 u; } pk;
#pragma unroll
  for (int r = 0; r < 4; ++r)
    pk.h[r] = (__bf16)fmaxf(a[r] * s4[r] + b4[r], 0.f);
  *(uint2*)(out + row * CO + c4) = pk.u;
}

// ---------------- up_combine: y4[f,co] = relu(bn4( sum_{tap,2x2} w_bilin * D )) ----------------
// D: [n][1024 coarse px][9*256] fp32 ; y4: [n][65536][256] bf16
__global__ __launch_bounds__(256, 4)
void up_combine(const float* __restrict__ D, const float* __restrict__ sc,
                const float* __restrict__ bi, __bf16* __restrict__ y4) {
  const int tid = threadIdx.x;
  const int coq = blockIdx.x;   // 0..3 (64-co quarter)
  const int oy = blockIdx.y;    // fine row 0..255
  const int n = blockIdx.z;
  const int co = coq * 64 + (tid & 15) * 4;
  const int px0 = (tid >> 4) * 16;

  const v4f s4 = *(const v4f*)(sc + co);
  const v4f b4 = *(const v4f*)(bi + co);

  v4f acc[16];
#pragma unroll
  for (int j = 0; j < 16; ++j)
#pragma unroll
    for (int r = 0; r < 4; ++r) acc[j][r] = 0.f;

  const float* Dn = D + (size_t)n * 1024 * 2304;

#pragma unroll
  for (int ty = 0; ty < 3; ++ty) {
    int fy = oy + ty - 1;
    if (fy < 0 || fy > 255) continue;
    float syf = fy * (31.0f / 255.0f);
    int rA = (int)syf; float wy = syf - rA;
    int rB = rA < 31 ? rA + 1 : 31;
    float wA = 1.f - wy, wB = wy;
    const float* rowA = Dn + (size_t)rA * 32 * 2304;
    const float* rowB = Dn + (size_t)rB * 32 * 2304;
#pragma unroll
    for (int tx = 0; tx < 3; ++tx) {
      const int tco = (ty * 3 + tx) * 256 + co;
      int cur = -99;
      v4f a0{}, a1{}, b0{}, b1{};
#pragma unroll
      for (int j = 0; j < 16; ++j) {
        int fx = px0 + j + tx - 1;
        if (fx < 0 || fx > 255) continue;
        float sxf = fx * (31.0f / 255.0f);
        int c0 = (int)sxf; float wx = sxf - c0;
        if (c0 != cur) {
          cur = c0;
          int c1 = c0 < 31 ? c0 + 1 : 31;
          a0 = *(const v4f*)(rowA + (size_t)c0 * 2304 + tco);
          a1 = *(const v4f*)(rowA + (size_t)c1 * 2304 + tco);
          b0 = *(const v4f*)(rowB + (size_t)c0 * 2304 + tco);
          b1 = *(const v4f*)(rowB + (size_t)c1 * 2304 + tco);
        }
        float wxA = 1.f - wx;
        float cA = wA * wxA, cB = wA * wx, cC = wB * wxA, cD = wB * wx;
#pragma unroll
        for (int r = 0; r < 4; ++r)
          acc[j][r] += cA * a0[r] + cB * a1[r] + cC * b0[r] + cD * b1[r];
      }
    }
  }

  __bf16* ob = y4 + (((size_t)n * 65536 + (size_t)oy * 256 + px0) * 256 + co);
#pragma unroll
  for (int j = 0; j < 16; ++j) {
    union { __bf16 h[4]; uint2 u; } pk;
#pragma unroll
    for (int r = 0; r < 4; ++r) {
      float v = acc[j][r] * s4[r] + b4[r];
      pk.h[r] = (__bf16)fmaxf(v, 0.f);
    }
    *(uint2*)(ob + (size_t)j * 256) = pk.u;
  }
}

// ---------------- conv4b: 3x3 conv 256->19 on 256x256, fp32 NCHW out ----------------
__global__ __launch_bounds__(256, 4)
void conv4b_k(const __bf16* __restrict__ y4, const __bf16* __restrict__ wp,
              float* __restrict__ outp) {
  __shared__ __align__(16) __bf16 tile[2][816 * 8];
  const int tid = threadIdx.x;
  const int lane = tid & 63, wv = tid >> 6;
  const int ln = lane & 15, q = lane >> 4;
  const int xblk = blockIdx.x, strip = blockIdx.y, n = blockIdx.z;
  const int oy0 = strip * 4, ox0 = xblk * 32;

  for (int t = tid; t < 1632; t += 256) ((uint4*)tile)[t] = make_uint4(0, 0, 0, 0);

  v4f acc[2][2];
#pragma unroll
  for (int mf = 0; mf < 2; ++mf)
#pragma unroll
    for (int nf = 0; nf < 2; ++nf)
#pragma unroll
      for (int r = 0; r < 4; ++r) acc[mf][nf][r] = 0.f;

  const __bf16* pa[2];
#pragma unroll
  for (int mf = 0; mf < 2; ++mf)
    pa[mf] = wp + (size_t)(mf * 16 + ln) * 256 + q * 8;
  int pixb[2];
#pragma unroll
  for (int nf = 0; nf < 2; ++nf) {
    int n_l = wv * 32 + nf * 16 + ln;
    pixb[nf] = (n_l >> 5) * 34 + (n_l & 31);
  }
  const __bf16* src = y4 + (size_t)n * 65536 * 256;
  const int gx = ox0 - 1 + lane;
  const bool xin = (lane < 34) && (gx >= 0) && (gx < 256);
  __syncthreads();

  // stage chunk 0 -> buf 0
#pragma unroll
  for (int t2 = 0; t2 < 6; ++t2) {
    int y = oy0 - 1 + t2;
    if (y >= 0 && y < 256 && xin)
      g2l16(&tile[0][(wv * 204 + t2 * 34) * 8],
            src + ((size_t)(y * 256 + gx) * 256 + wv * 8));
  }
  __syncthreads();

  for (int kc = 0; kc < 8; ++kc) {
    const int tb = kc & 1;
    if (kc + 1 < 8) {
      const int c1 = (kc + 1) * 32;
#pragma unroll
      for (int t2 = 0; t2 < 6; ++t2) {
        int y = oy0 - 1 + t2;
        if (y >= 0 && y < 256 && xin)
          g2l16(&tile[tb ^ 1][(wv * 204 + t2 * 34) * 8],
                src + ((size_t)(y * 256 + gx) * 256 + c1 + wv * 8));
      }
    }
    const int ci0 = kc * 32;
#pragma unroll
    for (int tap = 0; tap < 9; ++tap) {
      const int ty = tap / 3, tx = tap % 3;
      v8bf bfr[2];
#pragma unroll
      for (int nf = 0; nf < 2; ++nf)
        bfr[nf] = *(const v8bf*)&tile[tb][(q * 204 + pixb[nf] + ty * 34 + tx) * 8];
      const size_t toff = (size_t)tap * 32 * 256 + ci0;
#pragma unroll
      for (int mf = 0; mf < 2; ++mf) {
        v8bf af = *(const v8bf*)(pa[mf] + toff);
#pragma unroll
        for (int nf = 0; nf < 2; ++nf)
          acc[mf][nf] = MFMA16(af, bfr[nf], acc[mf][nf]);
      }
    }
    __syncthreads();
  }

#pragma unroll
  for (int mf = 0; mf < 2; ++mf) {
    const int m_l = mf * 16 + q * 4;
#pragma unroll
    for (int nf = 0; nf < 2; ++nf) {
      const int n_l = wv * 32 + nf * 16 + ln;
      const int oy = oy0 + (n_l >> 5), ox = ox0 + (n_l & 31);
#pragma unroll
      for (int r = 0; r < 4; ++r) {
        int co = m_l + r;
        if (co < 19)
          outp[(((size_t)n * 19 + co) * 256 + oy) * 256 + ox] = acc[mf][nf][r];
      }
    }
  }
}

// ---------------- softmax kernels ----------------

__global__ void softmax1024(const float* __restrict__ S, __bf16* __restrict__ O) {
  __shared__ float red[256];
  const int row = blockIdx.x, tid = threadIdx.x;
  const float* p = S + (size_t)row * 1024;
  float v0 = p[tid], v1 = p[tid + 256], v2 = p[tid + 512], v3 = p[tid + 768];
  float m = fmaxf(fmaxf(v0, v1), fmaxf(v2, v3));
  red[tid] = m; __syncthreads();
  for (int s = 128; s > 0; s >>= 1) { if (tid < s) red[tid] = fmaxf(red[tid], red[tid + s]); __syncthreads(); }
  m = red[0]; __syncthreads();
  v0 = __expf(v0 - m); v1 = __expf(v1 - m); v2 = __expf(v2 - m); v3 = __expf(v3 - m);
  red[tid] = v0 + v1 + v2 + v3; __syncthreads();
  for (int s = 128; s > 0; s >>= 1) { if (tid < s) red[tid] += red[tid + s]; __syncthreads(); }
  float inv = 1.0f / red[0];
  __bf16* o = O + (size_t)row * 1024;
  o[tid] = (__bf16)(v0 * inv); o[tid + 256] = (__bf16)(v1 * inv);
  o[tid + 512] = (__bf16)(v2 * inv); o[tid + 768] = (__bf16)(v3 * inv);
}

// softmax rows of Scc[c][d] (512 wide), writes transposed: O[d*512+c] = Asm[c][d]
__global__ void softmaxT512(const float* __restrict__ S, __bf16* __restrict__ O) {
  __shared__ float red[256];
  const int row = blockIdx.x, tid = threadIdx.x;
  const float* p = S + (size_t)row * 512;
  float v0 = p[tid], v1 = p[tid + 256];
  float m = fmaxf(v0, v1);
  red[tid] = m; __syncthreads();
  for (int s = 128; s > 0; s >>= 1) { if (tid < s) red[tid] = fmaxf(red[tid], red[tid + s]); __syncthreads(); }
  m = red[0]; __syncthreads();
  v0 = __expf(v0 - m); v1 = __expf(v1 - m);
  red[tid] = v0 + v1; __syncthreads();
  for (int s = 128; s > 0; s >>= 1) { if (tid < s) red[tid] += red[tid + s]; __syncthreads(); }
  float inv = 1.0f / red[0];
  int n = row >> 9, c = row & 511;
  __bf16* o = O + (size_t)n * 262144 + c;
  o[(size_t)tid * 512] = (__bf16)(v0 * inv);
  o[(size_t)(tid + 256) * 512] = (__bf16)(v1 * inv);
}

// z = y1 + y2 + gamma*E + beta*X
__global__ void combine_z(const __bf16* __restrict__ y12, const __bf16* __restrict__ E,
                          const __bf16* __restrict__ X, const float* __restrict__ gp,
                          const float* __restrict__ bp, __bf16* __restrict__ z) {
  size_t i = (size_t)blockIdx.x * 256 + threadIdx.x;
  int pg = (int)(i >> 9), c = (int)(i & 511);
  float g = gp[0], b = bp[0];
  float v = (float)y12[(size_t)pg * 1024 + c] + (float)y12[(size_t)pg * 1024 + 512 + c] +
            g * (float)E[i] + b * (float)X[i];
  z[i] = (__bf16)v;
}

// ---------------- launcher ----------------

extern "C" void kernel_launch(void* const* d_in, const int* in_sizes, int n_in,
                              void* d_out, int out_size, void* d_ws, size_t ws_size,
                              hipStream_t stream) {
  const float* x    = (const float*)d_in[0];
  const float* w1   = (const float*)d_in[1];
  const float* bn1g = (const float*)d_in[2];
  const float* bn1b = (const float*)d_in[3];
  const float* bn1m = (const float*)d_in[4];
  const float* bn1v = (const float*)d_in[5];
  const float* w2   = (const float*)d_in[6];
  const float* bn2g = (const float*)d_in[7];
  const float* bn2b = (const float*)d_in[8];
  const float* bn2m = (const float*)d_in[9];
  const float* bn2v = (const float*)d_in[10];
  const float* wB   = (const float*)d_in[11];
  const float* gam  = (const float*)d_in[12];
  const float* bet  = (const float*)d_in[13];
  const float* w3   = (const float*)d_in[14];
  const float* bn3g = (const float*)d_in[15];
  const float* bn3b = (const float*)d_in[16];
  const float* bn3m = (const float*)d_in[17];
  const float* bn3v = (const float*)d_in[18];
  const float* w4a  = (const float*)d_in[19];
  const float* bn4g = (const float*)d_in[20];
  const float* bn4b = (const float*)d_in[21];
  const float* bn4m = (const float*)d_in[22];
  const float* bn4v = (const float*)d_in[23];
  const float* w4b  = (const float*)d_in[24];

  char* ws = (char*)d_ws;
  size_t off = 0;
  auto take = [&](size_t bytes) -> char* {
    char* p = ws + off;
    off += (bytes + 255) & ~(size_t)255;
    return p;
  };
  __bf16* w12b  = (__bf16*)take(9ULL * 1024 * 2048 * 2);
  __bf16* w3b   = (__bf16*)take(9ULL * 512 * 512 * 2);
  __bf16* w4ab  = (__bf16*)take(9ULL * 256 * 512 * 2);
  __bf16* w4bb  = (__bf16*)take(9ULL * 32 * 256 * 2);
  __bf16* wBb   = (__bf16*)take(512ULL * 512 * 2);
  float*  sc12  = (float*)take(1024 * 4);
  float*  bi12  = (float*)take(1024 * 4);
  float*  sc3   = (float*)take(512 * 4);
  float*  bi3   = (float*)take(512 * 4);
  float*  sc4   = (float*)take(256 * 4);
  float*  bi4   = (float*)take(256 * 4);
  __bf16* xb    = (__bf16*)take(4ULL * 1024 * 2048 * 2);
  __bf16* y12   = (__bf16*)take(4ULL * 1024 * 1024 * 2);
  __bf16* Bm_pc = (__bf16*)take(4ULL * 1024 * 512 * 2);
  __bf16* Bm_cp = (__bf16*)take(4ULL * 512 * 1024 * 2);
  float*  Smat  = (float*)take(4ULL * 1024 * 1024 * 4);
  __bf16* Ssm   = (__bf16*)take(4ULL * 1024 * 1024 * 2);
  __bf16* E_pc  = (__bf16*)take(4ULL * 1024 * 512 * 2);
  __bf16* y2t   = (__bf16*)take(4ULL * 512 * 1024 * 2);
  float*  Scc   = (float*)take(4ULL * 512 * 512 * 4);
  __bf16* AsmT  = (__bf16*)take(4ULL * 512 * 512 * 2);
  __bf16* X_pc  = (__bf16*)take(4ULL * 1024 * 512 * 2);
  __bf16* zb    = (__bf16*)take(4ULL * 1024 * 512 * 2);
  __bf16* y4    = (__bf16*)take(4ULL * 65536 * 256 * 2);
  __bf16* y3    = (__bf16*)take(4ULL * 1024 * 512 * 2);
  // D (coarse tap-GEMM output, 37.75 MB fp32) aliases the dead xb..Smat region.
  float* Dmat = (float*)xb;
  // Split-K conv partials alias y4 (134 MB): conv1+2 needs 64 MB, conv3 needs
  // 32 MB; both are dead before up_combine writes y4.
  float* partK = (float*)y4;

  // prep
  bnprep<<<2, 256, 0, stream>>>(bn1g, bn1b, bn1m, bn1v, sc12, bi12, 512);
  bnprep<<<2, 256, 0, stream>>>(bn2g, bn2b, bn2m, bn2v, sc12 + 512, bi12 + 512, 512);
  bnprep<<<2, 256, 0, stream>>>(bn3g, bn3b, bn3m, bn3v, sc3, bi3, 512);
  bnprep<<<1, 256, 0, stream>>>(bn4g, bn4b, bn4m, bn4v, sc4, bi4, 256);
  pack_w<<<4096, 256, 0, stream>>>(w1, w12b, 512, 512, 0, 1024, 2048, 9);
  pack_w<<<4096, 256, 0, stream>>>(w2, w12b, 512, 512, 512, 1024, 2048, 9);
  pack_w<<<1024, 256, 0, stream>>>(w3, w3b, 512, 512, 0, 512, 512, 9);
  pack_w<<<512, 256, 0, stream>>>(w4a, w4ab, 256, 256, 0, 256, 512, 9);
  pack_w<<<32, 256, 0, stream>>>(w4b, w4bb, 32, 19, 0, 32, 256, 9);
  pack_w<<<1024, 256, 0, stream>>>(wB, wBb, 512, 512, 0, 512, 512, 1);
  cast_x_k<<<dim3(16, 32, 4), 256, 0, stream>>>(x, xb);

  // conv1 + conv2 fused, split-K x4 -> fp32 partials -> bn+relu reduce
  conv3x3_sk<2048, 64, 4><<<dim3(32, 8, 4), 256, 0, stream>>>(xb, w12b, partK, 1024);
  reduce_bn_relu<1024, 4><<<4096, 256, 0, stream>>>(partK, sc12, bi12, y12);

  // position attention
  gemm_nt<<<dim3(8, 4, 4), 256, 0, stream>>>(wBb, y12, 0, 1048576, 512, 1024, 16, 2,
                                             Bm_pc, Bm_cp, 524288, 512);
  gemm_nt<<<dim3(8, 8, 4), 256, 0, stream>>>(Bm_pc, Bm_pc, 524288, 524288, 512, 512, 16, 1,
                                             Smat, nullptr, 1048576, 1024);
  softmax1024<<<4096, 256, 0, stream>>>(Smat, Ssm);
  gemm_nt<<<dim3(8, 4, 4), 256, 0, stream>>>(Bm_cp, Ssm, 524288, 1048576, 1024, 1024, 32, 0,
                                             E_pc, nullptr, 524288, 512);

  // channel attention
  trans_y2<<<dim3(16, 8, 4), 256, 0, stream>>>(y12, y2t);
  gemm_nt<<<dim3(4, 4, 4), 256, 0, stream>>>(y2t, y2t, 524288, 524288, 1024, 1024, 32, 1,
                                             Scc, nullptr, 262144, 512);
  softmaxT512<<<2048, 256, 0, stream>>>(Scc, AsmT);
  gemm_nt<<<dim3(8, 4, 4), 256, 0, stream>>>(AsmT, y12 + 512, 262144, 1048576, 512, 1024, 16, 0,
                                             X_pc, nullptr, 524288, 512);

  // z = pa + ca
  combine_z<<<8192, 256, 0, stream>>>(y12, E_pc, X_pc, gam, bet, zb);

  // conv3, split-K x4
  conv3x3_sk<512, 16, 4><<<dim3(32, 4, 4), 256, 0, stream>>>(zb, w3b, partK, 512);
  reduce_bn_relu<512, 4><<<2048, 256, 0, stream>>>(partK, sc3, bi3, y3);

  // conv4a factored through the linear upsample:
  //   D[n][coarse px][t*256+co] = sum_ci w4a[t,co,ci] * y3[n,px,ci]   (fp32)
  gemm_nt<<<dim3(8, 18, 4), 256, 0, stream>>>(w4ab, y3, 0, 524288, 512, 512, 16, 3,
                                              Dmat, nullptr, 2359296, 2304);
  //   y4[f,co] = relu(bn4( sum_{tap,2x2} w_bilin(f,tap) * D ))
  up_combine<<<dim3(4, 256, 4), 256, 0, stream>>>(Dmat, sc4, bi4, y4);

  // conv4b -> d_out (fp32 NCHW)
  conv4b_k<<<dim3(8, 64, 4), 256, 0, stream>>>(y4, w4bb, (float*)d_out);
}